// Round 1
// baseline (1024.235 us; speedup 1.0000x reference)
//
#include <hip/hip_runtime.h>
#include <math.h>

#define NN 4096
#define HD 128
#define NCAND 64
#define NCF 10
#define NSEG 8
#define NEGV (-1000000000.0f)

__device__ __forceinline__ float gelu_f(float x) {
    return 0.5f * x * (1.0f + erff(x * 0.7071067811865475f));
}

#define ACC8(r, a) \
    acc[r][0] += (a)*b0.x; acc[r][1] += (a)*b0.y; acc[r][2] += (a)*b0.z; acc[r][3] += (a)*b0.w; \
    acc[r][4] += (a)*b1.x; acc[r][5] += (a)*b1.y; acc[r][6] += (a)*b1.z; acc[r][7] += (a)*b1.w;

// ---------------------------------------------------------------------------
// small dense GEMM: out[n][t] = sum_k in[n][k] * W[t][k] (+ bias[t])
// 16 nodes per block, 256 threads. W staged k-major in LDS (stride 129).
// ---------------------------------------------------------------------------
template<int K>
__global__ __launch_bounds__(256) void small_gemm_k(
    const float* __restrict__ in, const float* __restrict__ W,
    const float* __restrict__ bias, float* __restrict__ out)
{
    extern __shared__ float smem[];
    float* W_s  = smem;               // [K][129] k-major
    float* in_s = smem + 128*129;     // [16][K]
    float* b_s  = in_s + 16*128;
    int tid = threadIdx.x;
    int n0 = blockIdx.x * 16;
    for (int e = tid; e < 128*K; e += 256) {
        int t = e / K, k = e - t*K;
        W_s[k*129 + t] = W[e];
    }
    for (int e = tid; e < 16*K; e += 256)
        in_s[e] = in[(long)n0*K + e];
    if (tid < 128) b_s[tid] = bias ? bias[tid] : 0.0f;
    __syncthreads();
    int sub = tid >> 7;
    int t = tid & 127;
    #pragma unroll
    for (int rr = 0; rr < 2; ++rr) {
        int r0 = sub*8 + rr*4;
        float a0=0.f, a1=0.f, a2=0.f, a3=0.f;
        #pragma unroll 8
        for (int k = 0; k < K; ++k) {
            float w = W_s[k*129 + t];
            a0 += in_s[(r0+0)*K + k] * w;
            a1 += in_s[(r0+1)*K + k] * w;
            a2 += in_s[(r0+2)*K + k] * w;
            a3 += in_s[(r0+3)*K + k] * w;
        }
        float b = b_s[t];
        out[(long)(n0+r0+0)*HD + t] = a0 + b;
        out[(long)(n0+r0+1)*HD + t] = a1 + b;
        out[(long)(n0+r0+2)*HD + t] = a2 + b;
        out[(long)(n0+r0+3)*HD + t] = a3 + b;
    }
}

// ---------------------------------------------------------------------------
// per-node attention scalars: s = h·a_src, d = h·a_dst, plus factored exps
// sd layout: [s, exp(s), exp(0.2s), d, exp(d), exp(0.2d)] each length NN
// ---------------------------------------------------------------------------
__global__ __launch_bounds__(256) void sd_k(
    const float* __restrict__ Hx, const float* __restrict__ a_s,
    const float* __restrict__ a_d, float* __restrict__ sd)
{
    __shared__ float rs[4], rd[4];
    int tid = threadIdx.x;
    int g = tid >> 7;
    int t = tid & 127;
    int node = blockIdx.x*2 + g;
    float v = Hx[(long)node*HD + t];
    float sp = v * a_s[t];
    float dp = v * a_d[t];
    #pragma unroll
    for (int off = 32; off > 0; off >>= 1) {
        sp += __shfl_xor(sp, off);
        dp += __shfl_xor(dp, off);
    }
    int wid = tid >> 6;
    if ((tid & 63) == 0) { rs[wid] = sp; rd[wid] = dp; }
    __syncthreads();
    if (t == 0) {
        float s = rs[2*g] + rs[2*g+1];
        float d = rd[2*g] + rd[2*g+1];
        sd[0*NN + node] = s;
        sd[1*NN + node] = expf(s);
        sd[2*NN + node] = expf(0.2f*s);
        sd[3*NN + node] = d;
        sd[4*NN + node] = expf(d);
        sd[5*NN + node] = expf(0.2f*d);
    }
}

// ---------------------------------------------------------------------------
// GAT aggregate, K-split: block = 64 rows x all 128 cols, seg = j-range of 512.
// Writes partial numerator [seg][N][H] and denominator [seg][N]. No atomics.
// ---------------------------------------------------------------------------
__global__ __launch_bounds__(256) void agg_k(
    const float* __restrict__ Hx, const int* __restrict__ adj,
    const float* __restrict__ sd, float* __restrict__ num_part,
    float* __restrict__ den_part)
{
    __shared__ __align__(16) float Bs[64*128];   // H rows for current j-chunk
    __shared__ float As[64*65];                  // weight tile, stride 65
    __shared__ float sA[64], EsA[64], esA[64];
    __shared__ float denred[256];
    const float* s_  = sd;
    const float* Es_ = sd + NN;
    const float* es_ = sd + 2*NN;
    const float* d_  = sd + 3*NN;
    const float* Ed_ = sd + 4*NN;
    const float* ed_ = sd + 5*NN;
    int tid = threadIdx.x;
    int i0 = blockIdx.x * 64;
    int seg = blockIdx.y;
    if (tid < 64) {
        sA[tid]  = s_[i0+tid];
        EsA[tid] = Es_[i0+tid];
        esA[tid] = es_[i0+tid];
    }
    int gi = tid >> 4, gj = tid & 15;
    int ir0 = gi*4, t0 = gj*4;
    int jj = tid & 63;
    int iw = tid >> 6;
    int ird = tid >> 2, jq = (tid & 3)*16;
    float acc[4][8];
    #pragma unroll
    for (int x = 0; x < 4; ++x)
        #pragma unroll
        for (int c = 0; c < 8; ++c) acc[x][c] = 0.f;
    float den_acc = 0.f;

    for (int jc = 0; jc < 8; ++jc) {
        int j0 = seg*512 + jc*64;
        __syncthreads();
        {   // stage B = Hx[j0..j0+63][:]
            const float4* src = (const float4*)(Hx + (long)j0*HD);
            float4* dst = (float4*)Bs;
            #pragma unroll
            for (int e = 0; e < 8; ++e) dst[tid + e*256] = src[tid + e*256];
        }
        // stage A: masked factored-exp attention weights
        float dj = d_[j0+jj], Edj = Ed_[j0+jj], edj = ed_[j0+jj];
        #pragma unroll
        for (int it = 0; it < 16; ++it) {
            int i = it*4 + iw;
            int a = adj[(long)(i0+i)*NN + j0 + jj];
            float w = 0.f;
            if (a != 0)
                w = (sA[i] + dj > 0.f) ? (EsA[i]*Edj) : (esA[i]*edj);
            As[i*65 + jj] = w;
        }
        __syncthreads();
        // denominator partial (each thread: 16 j's of one row-quarter)
        #pragma unroll
        for (int x = 0; x < 16; ++x) den_acc += As[ird*65 + jq + x];
        // FMA: 4 rows x 8 cols per thread
        #pragma unroll 4
        for (int j = 0; j < 64; ++j) {
            float a0 = As[(ir0+0)*65 + j];
            float a1 = As[(ir0+1)*65 + j];
            float a2 = As[(ir0+2)*65 + j];
            float a3 = As[(ir0+3)*65 + j];
            float4 b0 = *(const float4*)&Bs[j*HD + t0];
            float4 b1 = *(const float4*)&Bs[j*HD + t0 + 64];
            ACC8(0, a0) ACC8(1, a1) ACC8(2, a2) ACC8(3, a3)
        }
    }
    long base = (long)seg*NN*HD;
    #pragma unroll
    for (int x = 0; x < 4; ++x) {
        float4 o0 = make_float4(acc[x][0],acc[x][1],acc[x][2],acc[x][3]);
        float4 o1 = make_float4(acc[x][4],acc[x][5],acc[x][6],acc[x][7]);
        *(float4*)(num_part + base + (long)(i0+ir0+x)*HD + t0)      = o0;
        *(float4*)(num_part + base + (long)(i0+ir0+x)*HD + t0 + 64) = o1;
    }
    denred[tid] = den_acc;
    __syncthreads();
    if (tid < 64)
        den_part[seg*NN + i0 + tid] =
            denred[tid*4] + denred[tid*4+1] + denred[tid*4+2] + denred[tid*4+3];
}

// ---------------------------------------------------------------------------
// G = relu(sum_seg num / sum_seg den)
// ---------------------------------------------------------------------------
__global__ __launch_bounds__(128) void reduce_relu_k(
    const float* __restrict__ num_part, const float* __restrict__ den_part,
    float* __restrict__ G)
{
    int row = blockIdx.x, t = threadIdx.x;
    float n = 0.f, d = 0.f;
    #pragma unroll
    for (int s = 0; s < NSEG; ++s) {
        n += num_part[(long)s*NN*HD + (long)row*HD + t];
        d += den_part[s*NN + row];
    }
    float v = (d > 0.f) ? n/d : 0.f;
    G[(long)row*HD + t] = fmaxf(v, 0.f);
}

// ---------------------------------------------------------------------------
// layer-2 epilogue: v = relu(num/den) + G1; LayerNorm -> HLN
// ---------------------------------------------------------------------------
__global__ __launch_bounds__(128) void reduce_ln_k(
    const float* __restrict__ num_part, const float* __restrict__ den_part,
    const float* __restrict__ G1, const float* __restrict__ ln_w,
    const float* __restrict__ ln_b, float* __restrict__ HLN)
{
    __shared__ float r1[2], r2[2];
    int row = blockIdx.x, t = threadIdx.x;
    float n = 0.f, d = 0.f;
    #pragma unroll
    for (int s = 0; s < NSEG; ++s) {
        n += num_part[(long)s*NN*HD + (long)row*HD + t];
        d += den_part[s*NN + row];
    }
    float v = (d > 0.f) ? n/d : 0.f;
    v = fmaxf(v, 0.f) + G1[(long)row*HD + t];
    float sum = v, sq = v*v;
    #pragma unroll
    for (int off = 32; off > 0; off >>= 1) {
        sum += __shfl_xor(sum, off);
        sq  += __shfl_xor(sq, off);
    }
    int wid = t >> 6;
    if ((t & 63) == 0) { r1[wid] = sum; r2[wid] = sq; }
    __syncthreads();
    float mu  = (r1[0]+r1[1]) * (1.0f/128.0f);
    float var = (r2[0]+r2[1]) * (1.0f/128.0f) - mu*mu;
    HLN[(long)row*HD + t] = (v - mu) * rsqrtf(var + 1e-5f) * ln_w[t] + ln_b[t];
}

// ---------------------------------------------------------------------------
// tile GEMM helper: 4 rows x 8 cols per thread, A stride SA, B k-major stride 132
// ---------------------------------------------------------------------------
template<int K, int SA>
__device__ __forceinline__ void tile_gemm(const float* A_s, const float* B_s,
                                          int cr0, int t0, float acc[4][8])
{
    #pragma unroll 2
    for (int k = 0; k < K; ++k) {
        float a0 = A_s[(cr0+0)*SA + k];
        float a1 = A_s[(cr0+1)*SA + k];
        float a2 = A_s[(cr0+2)*SA + k];
        float a3 = A_s[(cr0+3)*SA + k];
        float4 b0 = *(const float4*)&B_s[k*132 + t0];
        float4 b1 = *(const float4*)&B_s[k*132 + t0 + 64];
        ACC8(0, a0) ACC8(1, a1) ACC8(2, a2) ACC8(3, a3)
    }
}

// ---------------------------------------------------------------------------
// fused candidate head: one block per node, 256 threads.
// cand1=gelu(cf@Wc1^T+bc1); cand2=gelu(cand1@Wc2^T+bc2);
// Weff[h,k]=q_k*Ws1[h,k]+Ws1[h,k+128]; score=gelu(cand2@Weff^T+bs1);
// logit = score@Ws2^T + bs2 + bias(cf); masked output.
// ---------------------------------------------------------------------------
__global__ __launch_bounds__(256) void cand_k(
    const float* __restrict__ cf, const float* __restrict__ am,
    const float* __restrict__ Qb,
    const float* __restrict__ Wc1, const float* __restrict__ bc1,
    const float* __restrict__ Wc2, const float* __restrict__ bc2,
    const float* __restrict__ Ws1, const float* __restrict__ bs1,
    const float* __restrict__ Ws2, const float* __restrict__ bs2,
    float* __restrict__ out)
{
    extern __shared__ float smem[];
    float* W_s   = smem;                 // [128][132] k-major (Wc1 -> Wc2 -> Weff)
    float* c_s   = W_s + 128*132;        // [64][129]  cand1 -> cand2
    float* cf_s  = c_s + 64*129;         // [64][11]
    float* b1_s  = cf_s + 64*11;
    float* b2_s  = b1_s + 128;
    float* bs1_s = b2_s + 128;
    float* ws2_s = bs1_s + 128;
    float* q_s   = ws2_s + 128;
    float* red_s = q_s + 128;            // [64][16]
    int tid = threadIdx.x;
    int node = blockIdx.x;

    for (int e = tid; e < NCAND*NCF; e += 256) {
        int c = e / NCF, k = e - c*NCF;
        cf_s[c*11 + k] = cf[(long)node*NCAND*NCF + e];
    }
    if (tid < 128) {
        b1_s[tid]  = bc1[tid];
        b2_s[tid]  = bc2[tid];
        bs1_s[tid] = bs1[tid];
        ws2_s[tid] = Ws2[tid];
        q_s[tid]   = Qb[(long)node*HD + tid];
    }
    for (int e = tid; e < 128*NCF; e += 256) {
        int t = e / NCF, k = e - t*NCF;
        W_s[k*132 + t] = Wc1[e];
    }
    __syncthreads();

    int gi = tid >> 4, gj = tid & 15;
    int cr0 = gi*4, t0 = gj*4;

    // GEMM1: cand1
    {
        float acc[4][8];
        #pragma unroll
        for (int x = 0; x < 4; ++x)
            #pragma unroll
            for (int c = 0; c < 8; ++c) acc[x][c] = 0.f;
        tile_gemm<NCF, 11>(cf_s, W_s, cr0, t0, acc);
        #pragma unroll
        for (int x = 0; x < 4; ++x)
            #pragma unroll
            for (int c = 0; c < 4; ++c) {
                c_s[(cr0+x)*129 + t0 + c]      = gelu_f(acc[x][c]   + b1_s[t0+c]);
                c_s[(cr0+x)*129 + t0 + 64 + c] = gelu_f(acc[x][4+c] + b1_s[t0+64+c]);
            }
    }
    __syncthreads();
    // restage W_s with Wc2 (k-major)
    for (int e = tid; e < 128*128; e += 256) {
        int t = e >> 7, k = e & 127;
        W_s[k*132 + t] = Wc2[e];
    }
    __syncthreads();
    // GEMM2: cand2 (held in registers)
    float acc2[4][8];
    #pragma unroll
    for (int x = 0; x < 4; ++x)
        #pragma unroll
        for (int c = 0; c < 8; ++c) acc2[x][c] = 0.f;
    tile_gemm<128, 129>(c_s, W_s, cr0, t0, acc2);
    __syncthreads();   // everyone done reading c_s / W_s
    // write cand2 back; build Weff
    #pragma unroll
    for (int x = 0; x < 4; ++x)
        #pragma unroll
        for (int c = 0; c < 4; ++c) {
            c_s[(cr0+x)*129 + t0 + c]      = gelu_f(acc2[x][c]   + b2_s[t0+c]);
            c_s[(cr0+x)*129 + t0 + 64 + c] = gelu_f(acc2[x][4+c] + b2_s[t0+64+c]);
        }
    for (int e = tid; e < 128*128; e += 256) {
        int h = e >> 7, k = e & 127;
        W_s[k*132 + h] = q_s[k]*Ws1[(long)h*256 + k] + Ws1[(long)h*256 + 128 + k];
    }
    __syncthreads();
    // GEMM3: scoring
    float acc3[4][8];
    #pragma unroll
    for (int x = 0; x < 4; ++x)
        #pragma unroll
        for (int c = 0; c < 8; ++c) acc3[x][c] = 0.f;
    tile_gemm<128, 129>(c_s, W_s, cr0, t0, acc3);
    #pragma unroll
    for (int x = 0; x < 4; ++x) {
        float p = 0.f;
        #pragma unroll
        for (int c = 0; c < 4; ++c) {
            p += gelu_f(acc3[x][c]   + bs1_s[t0+c])    * ws2_s[t0+c];
            p += gelu_f(acc3[x][4+c] + bs1_s[t0+64+c]) * ws2_s[t0+64+c];
        }
        red_s[(cr0+x)*16 + gj] = p;
    }
    __syncthreads();
    if (tid < 64) {
        int c = tid;
        float lg = 0.f;
        #pragma unroll
        for (int q = 0; q < 16; ++q) lg += red_s[c*16 + q];
        lg += bs2[0];
        const float* r = &cf_s[c*11];
        lg += 20.0f*r[0] + 4.0f*r[4] + 1.5f*r[5] + 1.5f*r[1] - 1.5f*r[2]
            + 1.2f*r[6] + 2.5f*r[7] + 1.6f*r[8] + 1.2f*r[9];
        float m = am[(long)node*NCAND + c];
        float tot = m;
        #pragma unroll
        for (int off = 32; off > 0; off >>= 1) tot += __shfl_xor(tot, off);
        if (c == 0 && tot <= 0.f) m = 1.0f;
        out[(long)node*NCAND + c] = (m > 0.f) ? lg : NEGV;
    }
}

// ---------------------------------------------------------------------------
extern "C" void kernel_launch(void* const* d_in, const int* in_sizes, int n_in,
                              void* d_out, int out_size, void* d_ws, size_t ws_size,
                              hipStream_t stream)
{
    const float* X   = (const float*)d_in[0];
    const float* CF  = (const float*)d_in[1];
    const int*   ADJ = (const int*)d_in[2];
    const float* AM  = (const float*)d_in[3];
    const float* W1  = (const float*)d_in[4];
    const float* A1S = (const float*)d_in[5];
    const float* A1D = (const float*)d_in[6];
    const float* W2  = (const float*)d_in[7];
    const float* A2S = (const float*)d_in[8];
    const float* A2D = (const float*)d_in[9];
    const float* LNW = (const float*)d_in[10];
    const float* LNB = (const float*)d_in[11];
    const float* WC1 = (const float*)d_in[12];
    const float* BC1 = (const float*)d_in[13];
    const float* WC2 = (const float*)d_in[14];
    const float* BC2 = (const float*)d_in[15];
    const float* WQ  = (const float*)d_in[16];
    const float* BQ  = (const float*)d_in[17];
    const float* WS1 = (const float*)d_in[18];
    const float* BS1 = (const float*)d_in[19];
    const float* WS2 = (const float*)d_in[20];
    const float* BS2 = (const float*)d_in[21];
    float* OUT = (float*)d_out;

    float* ws  = (float*)d_ws;
    float* H1   = ws;                    // 4096*128
    float* G1   = ws + 524288;           // 4096*128
    float* H2   = ws + 1048576;          // 4096*128
    float* HLN  = ws + 1572864;          // 4096*128
    float* Qb   = ws + 2097152;          // 4096*128
    float* sd1  = ws + 2621440;          // 6*4096
    float* sd2  = ws + 2646016;          // 6*4096
    float* nump = ws + 2670592;          // 8*4096*128
    float* denp = ws + 6864896;          // 8*4096

    const int SG_SMEM = (128*129 + 16*128 + 128) * 4;          // 74752 B
    const int CAND_SMEM = (128*132 + 64*129 + 64*11 + 5*128 + 64*16) * 4; // 110080 B

    // GAT layer 1
    small_gemm_k<64><<<256, 256, SG_SMEM, stream>>>(X, W1, nullptr, H1);
    sd_k<<<2048, 256, 0, stream>>>(H1, A1S, A1D, sd1);
    agg_k<<<dim3(64, NSEG), 256, 0, stream>>>(H1, ADJ, sd1, nump, denp);
    reduce_relu_k<<<NN, 128, 0, stream>>>(nump, denp, G1);
    // GAT layer 2 + residual + LN
    small_gemm_k<128><<<256, 256, SG_SMEM, stream>>>(G1, W2, nullptr, H2);
    sd_k<<<2048, 256, 0, stream>>>(H2, A2S, A2D, sd2);
    agg_k<<<dim3(64, NSEG), 256, 0, stream>>>(H2, ADJ, sd2, nump, denp);
    reduce_ln_k<<<NN, 128, 0, stream>>>(nump, denp, G1, LNW, LNB, HLN);
    // query projection
    small_gemm_k<128><<<256, 256, SG_SMEM, stream>>>(HLN, WQ, BQ, Qb);
    // fused candidate head
    cand_k<<<NN, 256, CAND_SMEM, stream>>>(CF, AM, Qb, WC1, BC1, WC2, BC2,
                                           WS1, BS1, WS2, BS2, OUT);
}

// Round 2
// 545.759 us; speedup vs baseline: 1.8767x; 1.8767x over previous
//
#include <hip/hip_runtime.h>
#include <math.h>

#define NN 4096
#define HD 128
#define NCAND 64
#define NCF 10
#define NSEG 8
#define NEGV (-1000000000.0f)

typedef __attribute__((ext_vector_type(8))) short short8_t;
typedef __attribute__((ext_vector_type(4))) float f32x4_t;

__device__ __forceinline__ float gelu_f(float x) {
    return 0.5f * x * (1.0f + erff(x * 0.7071067811865475f));
}

__device__ __forceinline__ short f2bf(float f) {
    union { float f; unsigned u; } v; v.f = f;
    unsigned r = (v.u + 0x7FFFu + ((v.u >> 16) & 1u)) >> 16;
    return (short)r;
}

#define ACC8(r, a) \
    acc[r][0] += (a)*b0.x; acc[r][1] += (a)*b0.y; acc[r][2] += (a)*b0.z; acc[r][3] += (a)*b0.w; \
    acc[r][4] += (a)*b1.x; acc[r][5] += (a)*b1.y; acc[r][6] += (a)*b1.z; acc[r][7] += (a)*b1.w;

// ---------------------------------------------------------------------------
// small dense GEMM: out[n][t] = sum_k in[n][k] * W[t][k] (+ bias[t])
// ---------------------------------------------------------------------------
template<int K>
__global__ __launch_bounds__(256) void small_gemm_k(
    const float* __restrict__ in, const float* __restrict__ W,
    const float* __restrict__ bias, float* __restrict__ out)
{
    extern __shared__ float smem[];
    float* W_s  = smem;               // [K][129] k-major
    float* in_s = smem + 128*129;     // [16][K]
    float* b_s  = in_s + 16*128;
    int tid = threadIdx.x;
    int n0 = blockIdx.x * 16;
    for (int e = tid; e < 128*K; e += 256) {
        int t = e / K, k = e - t*K;
        W_s[k*129 + t] = W[e];
    }
    for (int e = tid; e < 16*K; e += 256)
        in_s[e] = in[(long)n0*K + e];
    if (tid < 128) b_s[tid] = bias ? bias[tid] : 0.0f;
    __syncthreads();
    int sub = tid >> 7;
    int t = tid & 127;
    #pragma unroll
    for (int rr = 0; rr < 2; ++rr) {
        int r0 = sub*8 + rr*4;
        float a0=0.f, a1=0.f, a2=0.f, a3=0.f;
        #pragma unroll 8
        for (int k = 0; k < K; ++k) {
            float w = W_s[k*129 + t];
            a0 += in_s[(r0+0)*K + k] * w;
            a1 += in_s[(r0+1)*K + k] * w;
            a2 += in_s[(r0+2)*K + k] * w;
            a3 += in_s[(r0+3)*K + k] * w;
        }
        float b = b_s[t];
        out[(long)(n0+r0+0)*HD + t] = a0 + b;
        out[(long)(n0+r0+1)*HD + t] = a1 + b;
        out[(long)(n0+r0+2)*HD + t] = a2 + b;
        out[(long)(n0+r0+3)*HD + t] = a3 + b;
    }
}

// ---------------------------------------------------------------------------
// per-node attention scalars
// ---------------------------------------------------------------------------
__global__ __launch_bounds__(256) void sd_k(
    const float* __restrict__ Hx, const float* __restrict__ a_s,
    const float* __restrict__ a_d, float* __restrict__ sd)
{
    __shared__ float rs[4], rd[4];
    int tid = threadIdx.x;
    int g = tid >> 7;
    int t = tid & 127;
    int node = blockIdx.x*2 + g;
    float v = Hx[(long)node*HD + t];
    float sp = v * a_s[t];
    float dp = v * a_d[t];
    #pragma unroll
    for (int off = 32; off > 0; off >>= 1) {
        sp += __shfl_xor(sp, off);
        dp += __shfl_xor(dp, off);
    }
    int wid = tid >> 6;
    if ((tid & 63) == 0) { rs[wid] = sp; rd[wid] = dp; }
    __syncthreads();
    if (t == 0) {
        float s = rs[2*g] + rs[2*g+1];
        float d = rd[2*g] + rd[2*g+1];
        sd[0*NN + node] = s;
        sd[1*NN + node] = expf(s);
        sd[2*NN + node] = expf(0.2f*s);
        sd[3*NN + node] = d;
        sd[4*NN + node] = expf(d);
        sd[5*NN + node] = expf(0.2f*d);
    }
}

// ---------------------------------------------------------------------------
// GAT aggregate, K-split (unchanged from round 1)
// ---------------------------------------------------------------------------
__global__ __launch_bounds__(256) void agg_k(
    const float* __restrict__ Hx, const int* __restrict__ adj,
    const float* __restrict__ sd, float* __restrict__ num_part,
    float* __restrict__ den_part)
{
    __shared__ __align__(16) float Bs[64*128];
    __shared__ float As[64*65];
    __shared__ float sA[64], EsA[64], esA[64];
    __shared__ float denred[256];
    const float* s_  = sd;
    const float* Es_ = sd + NN;
    const float* es_ = sd + 2*NN;
    const float* d_  = sd + 3*NN;
    const float* Ed_ = sd + 4*NN;
    const float* ed_ = sd + 5*NN;
    int tid = threadIdx.x;
    int i0 = blockIdx.x * 64;
    int seg = blockIdx.y;
    if (tid < 64) {
        sA[tid]  = s_[i0+tid];
        EsA[tid] = Es_[i0+tid];
        esA[tid] = es_[i0+tid];
    }
    int gi = tid >> 4, gj = tid & 15;
    int ir0 = gi*4, t0 = gj*4;
    int jj = tid & 63;
    int iw = tid >> 6;
    int ird = tid >> 2, jq = (tid & 3)*16;
    float acc[4][8];
    #pragma unroll
    for (int x = 0; x < 4; ++x)
        #pragma unroll
        for (int c = 0; c < 8; ++c) acc[x][c] = 0.f;
    float den_acc = 0.f;

    for (int jc = 0; jc < 8; ++jc) {
        int j0 = seg*512 + jc*64;
        __syncthreads();
        {
            const float4* src = (const float4*)(Hx + (long)j0*HD);
            float4* dst = (float4*)Bs;
            #pragma unroll
            for (int e = 0; e < 8; ++e) dst[tid + e*256] = src[tid + e*256];
        }
        float dj = d_[j0+jj], Edj = Ed_[j0+jj], edj = ed_[j0+jj];
        #pragma unroll
        for (int it = 0; it < 16; ++it) {
            int i = it*4 + iw;
            int a = adj[(long)(i0+i)*NN + j0 + jj];
            float w = 0.f;
            if (a != 0)
                w = (sA[i] + dj > 0.f) ? (EsA[i]*Edj) : (esA[i]*edj);
            As[i*65 + jj] = w;
        }
        __syncthreads();
        #pragma unroll
        for (int x = 0; x < 16; ++x) den_acc += As[ird*65 + jq + x];
        #pragma unroll 4
        for (int j = 0; j < 64; ++j) {
            float a0 = As[(ir0+0)*65 + j];
            float a1 = As[(ir0+1)*65 + j];
            float a2 = As[(ir0+2)*65 + j];
            float a3 = As[(ir0+3)*65 + j];
            float4 b0 = *(const float4*)&Bs[j*HD + t0];
            float4 b1 = *(const float4*)&Bs[j*HD + t0 + 64];
            ACC8(0, a0) ACC8(1, a1) ACC8(2, a2) ACC8(3, a3)
        }
    }
    long base = (long)seg*NN*HD;
    #pragma unroll
    for (int x = 0; x < 4; ++x) {
        float4 o0 = make_float4(acc[x][0],acc[x][1],acc[x][2],acc[x][3]);
        float4 o1 = make_float4(acc[x][4],acc[x][5],acc[x][6],acc[x][7]);
        *(float4*)(num_part + base + (long)(i0+ir0+x)*HD + t0)      = o0;
        *(float4*)(num_part + base + (long)(i0+ir0+x)*HD + t0 + 64) = o1;
    }
    denred[tid] = den_acc;
    __syncthreads();
    if (tid < 64)
        den_part[seg*NN + i0 + tid] =
            denred[tid*4] + denred[tid*4+1] + denred[tid*4+2] + denred[tid*4+3];
}

__global__ __launch_bounds__(128) void reduce_relu_k(
    const float* __restrict__ num_part, const float* __restrict__ den_part,
    float* __restrict__ G)
{
    int row = blockIdx.x, t = threadIdx.x;
    float n = 0.f, d = 0.f;
    #pragma unroll
    for (int s = 0; s < NSEG; ++s) {
        n += num_part[(long)s*NN*HD + (long)row*HD + t];
        d += den_part[s*NN + row];
    }
    float v = (d > 0.f) ? n/d : 0.f;
    G[(long)row*HD + t] = fmaxf(v, 0.f);
}

__global__ __launch_bounds__(128) void reduce_ln_k(
    const float* __restrict__ num_part, const float* __restrict__ den_part,
    const float* __restrict__ G1, const float* __restrict__ ln_w,
    const float* __restrict__ ln_b, float* __restrict__ HLN)
{
    __shared__ float r1[2], r2[2];
    int row = blockIdx.x, t = threadIdx.x;
    float n = 0.f, d = 0.f;
    #pragma unroll
    for (int s = 0; s < NSEG; ++s) {
        n += num_part[(long)s*NN*HD + (long)row*HD + t];
        d += den_part[s*NN + row];
    }
    float v = (d > 0.f) ? n/d : 0.f;
    v = fmaxf(v, 0.f) + G1[(long)row*HD + t];
    float sum = v, sq = v*v;
    #pragma unroll
    for (int off = 32; off > 0; off >>= 1) {
        sum += __shfl_xor(sum, off);
        sq  += __shfl_xor(sq, off);
    }
    int wid = t >> 6;
    if ((t & 63) == 0) { r1[wid] = sum; r2[wid] = sq; }
    __syncthreads();
    float mu  = (r1[0]+r1[1]) * (1.0f/128.0f);
    float var = (r2[0]+r2[1]) * (1.0f/128.0f) - mu*mu;
    HLN[(long)row*HD + t] = (v - mu) * rsqrtf(var + 1e-5f) * ln_w[t] + ln_b[t];
}

// ---------------------------------------------------------------------------
// MFMA tile helper: 64x128 output, A[64][K=128] bf16 (stride 136),
// B[128 n][128 k] bf16 (stride 136). Wave w covers m-tiles {2(w>>1),+1},
// n-tiles {4(w&1)..+3}. acc[2][4] of f32x4.
// ---------------------------------------------------------------------------
__device__ __forceinline__ void mfma_64x128(
    const short* A_s, const short* B_s, int mt0, int nt0, int lm, int qd,
    f32x4_t acc[2][4])
{
    #pragma unroll
    for (int kc = 0; kc < 4; ++kc) {
        int k0 = kc*32 + qd*8;
        short8_t a0 = *(const short8_t*)&A_s[(mt0*16 + lm)*136 + k0];
        short8_t a1 = *(const short8_t*)&A_s[((mt0+1)*16 + lm)*136 + k0];
        #pragma unroll
        for (int in = 0; in < 4; ++in) {
            short8_t b = *(const short8_t*)&B_s[((nt0+in)*16 + lm)*136 + k0];
            acc[0][in] = __builtin_amdgcn_mfma_f32_16x16x32_bf16(a0, b, acc[0][in], 0, 0, 0);
            acc[1][in] = __builtin_amdgcn_mfma_f32_16x16x32_bf16(a1, b, acc[1][in], 0, 0, 0);
        }
    }
}

// ---------------------------------------------------------------------------
// fused candidate head, MFMA version. One block (256 thr) per node.
// cand1 = gelu(cf@Wc1^T+bc1)            (VALU, K=10)
// cand2 = gelu(cand1@Wc2^T+bc2)         (MFMA bf16)
// Weff[h,k] = q[k]*Ws1[h,k]+Ws1[h,k+128]  (staged f32->bf16)
// score = gelu(cand2@Weff^T+bs1); logit = score@Ws2^T+bs2+bias; mask.
// LDS ~71 KB -> 2 blocks/CU.
// ---------------------------------------------------------------------------
__global__ __launch_bounds__(256) void cand_mfma_k(
    const float* __restrict__ cf, const float* __restrict__ am,
    const float* __restrict__ Qb,
    const float* __restrict__ Wc1, const float* __restrict__ bc1,
    const float* __restrict__ Wc2, const float* __restrict__ bc2,
    const float* __restrict__ Ws1, const float* __restrict__ bs1,
    const float* __restrict__ Ws2, const float* __restrict__ bs2,
    float* __restrict__ out)
{
    __shared__ __align__(16) short W_s[128*136];    // bf16 weights (Wc2 then Weff)
    __shared__ __align__(16) short cand_s[64*136];  // bf16 cand1 then cand2
    __shared__ float cf_s[64*12];
    __shared__ float wc1_s[128*10];
    __shared__ float red_s[64*33];
    __shared__ float b1_s[128], b2_s[128], bs1_s[128], ws2_s[128], q_s[128];

    int tid = threadIdx.x;
    int node = blockIdx.x;

    for (int e = tid; e < NCAND*NCF; e += 256) {
        int c = e / NCF, k = e - c*NCF;
        cf_s[c*12 + k] = cf[(long)node*NCAND*NCF + e];
    }
    for (int e = tid; e < 128*NCF; e += 256) wc1_s[e] = Wc1[e];
    if (tid < 128) {
        b1_s[tid]  = bc1[tid];
        b2_s[tid]  = bc2[tid];
        bs1_s[tid] = bs1[tid];
        ws2_s[tid] = Ws2[tid];
        q_s[tid]   = Qb[(long)node*HD + tid];
    }
    // stage Wc2 (n-major [h][k]) as bf16
    for (int e = tid; e < 128*128; e += 256) {
        int h = e >> 7, k = e & 127;
        W_s[h*136 + k] = f2bf(Wc2[e]);
    }
    __syncthreads();

    // GEMM1: cand1 (K=10, VALU)
    for (int e = tid; e < 64*128; e += 256) {
        int c = e >> 7, t = e & 127;
        float a = b1_s[t];
        #pragma unroll
        for (int k = 0; k < NCF; ++k)
            a += cf_s[c*12 + k] * wc1_s[t*10 + k];
        cand_s[c*136 + t] = f2bf(gelu_f(a));
    }
    __syncthreads();

    int w  = tid >> 6;
    int l  = tid & 63;
    int lm = l & 15;
    int qd = l >> 4;
    int mt0 = (w >> 1) * 2;
    int nt0 = (w & 1) * 4;

    // GEMM2: cand2 = gelu(cand1 @ Wc2^T + bc2)
    f32x4_t acc[2][4];
    #pragma unroll
    for (int im = 0; im < 2; ++im)
        #pragma unroll
        for (int in = 0; in < 4; ++in)
            acc[im][in] = (f32x4_t){0.f, 0.f, 0.f, 0.f};
    mfma_64x128(cand_s, W_s, mt0, nt0, lm, qd, acc);
    __syncthreads();   // all waves done reading cand_s / W_s

    // write cand2 back (bf16), stage Weff
    #pragma unroll
    for (int im = 0; im < 2; ++im)
        #pragma unroll
        for (int in = 0; in < 4; ++in)
            #pragma unroll
            for (int r = 0; r < 4; ++r) {
                int m = (mt0+im)*16 + qd*4 + r;
                int n = (nt0+in)*16 + lm;
                cand_s[m*136 + n] = f2bf(gelu_f(acc[im][in][r] + b2_s[n]));
            }
    for (int e = tid; e < 128*128; e += 256) {
        int h = e >> 7, k = e & 127;
        W_s[h*136 + k] = f2bf(q_s[k]*Ws1[(long)h*256 + k] + Ws1[(long)h*256 + 128 + k]);
    }
    __syncthreads();

    // GEMM3: score = cand2 @ Weff^T
    #pragma unroll
    for (int im = 0; im < 2; ++im)
        #pragma unroll
        for (int in = 0; in < 4; ++in)
            acc[im][in] = (f32x4_t){0.f, 0.f, 0.f, 0.f};
    mfma_64x128(cand_s, W_s, mt0, nt0, lm, qd, acc);

    // epilogue: partial logits
    #pragma unroll
    for (int im = 0; im < 2; ++im)
        #pragma unroll
        for (int r = 0; r < 4; ++r) {
            float p = 0.f;
            #pragma unroll
            for (int in = 0; in < 4; ++in) {
                int n = (nt0+in)*16 + lm;
                p += gelu_f(acc[im][in][r] + bs1_s[n]) * ws2_s[n];
            }
            int m = (mt0+im)*16 + qd*4 + r;
            red_s[m*33 + (w&1)*16 + lm] = p;
        }
    __syncthreads();

    if (tid < 64) {
        int c = tid;
        float lg = bs2[0];
        #pragma unroll
        for (int s = 0; s < 32; ++s) lg += red_s[c*33 + s];
        const float* r = &cf_s[c*12];
        lg += 20.0f*r[0] + 4.0f*r[4] + 1.5f*r[5] + 1.5f*r[1] - 1.5f*r[2]
            + 1.2f*r[6] + 2.5f*r[7] + 1.6f*r[8] + 1.2f*r[9];
        float m = am[(long)node*NCAND + c];
        float tot = m;
        #pragma unroll
        for (int off = 32; off > 0; off >>= 1) tot += __shfl_xor(tot, off);
        if (c == 0 && tot <= 0.f) m = 1.0f;
        out[(long)node*NCAND + c] = (m > 0.f) ? lg : NEGV;
    }
}

// ---------------------------------------------------------------------------
extern "C" void kernel_launch(void* const* d_in, const int* in_sizes, int n_in,
                              void* d_out, int out_size, void* d_ws, size_t ws_size,
                              hipStream_t stream)
{
    const float* X   = (const float*)d_in[0];
    const float* CF  = (const float*)d_in[1];
    const int*   ADJ = (const int*)d_in[2];
    const float* AM  = (const float*)d_in[3];
    const float* W1  = (const float*)d_in[4];
    const float* A1S = (const float*)d_in[5];
    const float* A1D = (const float*)d_in[6];
    const float* W2  = (const float*)d_in[7];
    const float* A2S = (const float*)d_in[8];
    const float* A2D = (const float*)d_in[9];
    const float* LNW = (const float*)d_in[10];
    const float* LNB = (const float*)d_in[11];
    const float* WC1 = (const float*)d_in[12];
    const float* BC1 = (const float*)d_in[13];
    const float* WC2 = (const float*)d_in[14];
    const float* BC2 = (const float*)d_in[15];
    const float* WQ  = (const float*)d_in[16];
    const float* BQ  = (const float*)d_in[17];
    const float* WS1 = (const float*)d_in[18];
    const float* BS1 = (const float*)d_in[19];
    const float* WS2 = (const float*)d_in[20];
    const float* BS2 = (const float*)d_in[21];
    float* OUT = (float*)d_out;

    float* ws  = (float*)d_ws;
    float* H1   = ws;                    // 4096*128
    float* G1   = ws + 524288;
    float* H2   = ws + 1048576;
    float* HLN  = ws + 1572864;
    float* Qb   = ws + 2097152;
    float* sd1  = ws + 2621440;
    float* sd2  = ws + 2646016;
    float* nump = ws + 2670592;          // 8*4096*128
    float* denp = ws + 6864896;          // 8*4096

    const int SG_SMEM = (128*129 + 16*128 + 128) * 4;

    // GAT layer 1
    small_gemm_k<64><<<256, 256, SG_SMEM, stream>>>(X, W1, nullptr, H1);
    sd_k<<<2048, 256, 0, stream>>>(H1, A1S, A1D, sd1);
    agg_k<<<dim3(64, NSEG), 256, 0, stream>>>(H1, ADJ, sd1, nump, denp);
    reduce_relu_k<<<NN, 128, 0, stream>>>(nump, denp, G1);
    // GAT layer 2 + residual + LN
    small_gemm_k<128><<<256, 256, SG_SMEM, stream>>>(G1, W2, nullptr, H2);
    sd_k<<<2048, 256, 0, stream>>>(H2, A2S, A2D, sd2);
    agg_k<<<dim3(64, NSEG), 256, 0, stream>>>(H2, ADJ, sd2, nump, denp);
    reduce_ln_k<<<NN, 128, 0, stream>>>(nump, denp, G1, LNW, LNB, HLN);
    // query projection
    small_gemm_k<128><<<256, 256, SG_SMEM, stream>>>(HLN, WQ, BQ, Qb);
    // fused candidate head (MFMA)
    cand_mfma_k<<<NN, 256, 0, stream>>>(CF, AM, Qb, WC1, BC1, WC2, BC2,
                                        WS1, BS1, WS2, BS2, OUT);
}

// Round 3
// 433.850 us; speedup vs baseline: 2.3608x; 1.2579x over previous
//
#include <hip/hip_runtime.h>
#include <hip/hip_bf16.h>
#include <math.h>

#define NN 4096
#define HD 128
#define NCAND 64
#define NCF 10
#define NSEG 8
#define NEGV (-1000000000.0f)

typedef __attribute__((ext_vector_type(8))) short short8_t;
typedef __attribute__((ext_vector_type(4))) float f32x4_t;

// ---- bf16 helpers ---------------------------------------------------------
__device__ __forceinline__ short f2bf(float f) {
    union { float f; unsigned u; } v; v.f = f;
    unsigned r = (v.u + 0x7FFFu + ((v.u >> 16) & 1u)) >> 16;
    return (short)r;
}
__device__ __forceinline__ float bf2f(short s) {
    union { unsigned u; float f; } v; v.u = ((unsigned)(unsigned short)s) << 16;
    return v.f;
}
__device__ __forceinline__ unsigned pk2(float a, float b) {
    union { __hip_bfloat162 h; unsigned u; } v;
    v.h = __float22bfloat162_rn(make_float2(a, b));
    return v.u;
}

// fast gelu: tanh form, z2 = x*(A + B*x^2) already scaled by 2*log2(e)
__device__ __forceinline__ float gelu_f(float x) {
    const float A = 2.3022082f, B = 0.1029432f;
    float x2 = x * x;
    float z2 = x * (A + B * x2);
    float e  = __builtin_amdgcn_exp2f(z2);
    float r  = __builtin_amdgcn_rcpf(e + 1.0f);
    return x - x * r;
}

// ---------------------------------------------------------------------------
// small dense GEMM: out[n][t] = sum_k in[n][k] * W[t][k] (+ bias[t])
// ---------------------------------------------------------------------------
template<int K>
__global__ __launch_bounds__(256) void small_gemm_k(
    const float* __restrict__ in, const float* __restrict__ W,
    const float* __restrict__ bias, float* __restrict__ out)
{
    extern __shared__ float smem[];
    float* W_s  = smem;               // [K][129] k-major
    float* in_s = smem + 128*129;     // [16][K]
    float* b_s  = in_s + 16*128;
    int tid = threadIdx.x;
    int n0 = blockIdx.x * 16;
    for (int e = tid; e < 128*K; e += 256) {
        int t = e / K, k = e - t*K;
        W_s[k*129 + t] = W[e];
    }
    for (int e = tid; e < 16*K; e += 256)
        in_s[e] = in[(long)n0*K + e];
    if (tid < 128) b_s[tid] = bias ? bias[tid] : 0.0f;
    __syncthreads();
    int sub = tid >> 7;
    int t = tid & 127;
    #pragma unroll
    for (int rr = 0; rr < 2; ++rr) {
        int r0 = sub*8 + rr*4;
        float a0=0.f, a1=0.f, a2=0.f, a3=0.f;
        #pragma unroll 8
        for (int k = 0; k < K; ++k) {
            float w = W_s[k*129 + t];
            a0 += in_s[(r0+0)*K + k] * w;
            a1 += in_s[(r0+1)*K + k] * w;
            a2 += in_s[(r0+2)*K + k] * w;
            a3 += in_s[(r0+3)*K + k] * w;
        }
        float b = b_s[t];
        out[(long)(n0+r0+0)*HD + t] = a0 + b;
        out[(long)(n0+r0+1)*HD + t] = a1 + b;
        out[(long)(n0+r0+2)*HD + t] = a2 + b;
        out[(long)(n0+r0+3)*HD + t] = a3 + b;
    }
}

// ---------------------------------------------------------------------------
// pack adjacency into bitmask: adjb[i*128 + w] bit c = (adj[i*4096 + w*32+c]!=0)
// ---------------------------------------------------------------------------
__global__ __launch_bounds__(256) void pack_k(
    const int* __restrict__ adj, unsigned* __restrict__ adjb)
{
    long g = (long)blockIdx.x * 256 + threadIdx.x;   // 524288 words
    const int4* p = (const int4*)adj + g * 8;
    unsigned w = 0;
    #pragma unroll
    for (int e = 0; e < 8; ++e) {
        int4 v = p[e];
        w |= (unsigned)(v.x != 0) << (e*4 + 0);
        w |= (unsigned)(v.y != 0) << (e*4 + 1);
        w |= (unsigned)(v.z != 0) << (e*4 + 2);
        w |= (unsigned)(v.w != 0) << (e*4 + 3);
    }
    adjb[g] = w;
}

// ---------------------------------------------------------------------------
// weight prep: bf16 conversions; Wc1b zero-padded K 10->32;
// Wfused[h][0..127]=Ws1[h][128+j] (b part), [128..255]=Ws1[h][j] (a part)
// ---------------------------------------------------------------------------
__global__ __launch_bounds__(256) void wprep_k(
    const float* __restrict__ Wc1, const float* __restrict__ Wc2,
    const float* __restrict__ Ws1,
    short* __restrict__ Wc1b, short* __restrict__ Wc2b, short* __restrict__ Wfu)
{
    int g = blockIdx.x * 256 + threadIdx.x;
    int tot = gridDim.x * 256;
    for (int e = g; e < 128*32; e += tot) {
        int t = e >> 5, k = e & 31;
        Wc1b[e] = (k < NCF) ? f2bf(Wc1[t*NCF + k]) : (short)0;
    }
    for (int e = g; e < 128*128; e += tot) Wc2b[e] = f2bf(Wc2[e]);
    for (int e = g; e < 128*256; e += tot) {
        int h = e >> 8, j = e & 255;
        float v = (j < 128) ? Ws1[h*256 + 128 + j] : Ws1[h*256 + (j - 128)];
        Wfu[e] = f2bf(v);
    }
}

// ---------------------------------------------------------------------------
// prep: per-node attention scalars + transposed bf16 H  (replaces sd_k)
// sdv layout: [s, exp(s), exp(.2s), d, exp(d), exp(.2d)] x NN
// Htb: [128][4096] bf16 (h-major)
// ---------------------------------------------------------------------------
__global__ __launch_bounds__(256) void prep_k(
    const float* __restrict__ H, const float* __restrict__ a_s,
    const float* __restrict__ a_d, float* __restrict__ sdv,
    short* __restrict__ Htb)
{
    __shared__ __align__(16) float H_s[64*132];
    __shared__ float as_s[128], ad_s[128];
    int tid = threadIdx.x;
    int n0 = blockIdx.x * 64;
    if (tid < 128) { as_s[tid] = a_s[tid]; ad_s[tid] = a_d[tid]; }
    for (int e = tid; e < 2048; e += 256) {
        int n = e >> 5, h4 = e & 31;
        *(float4*)&H_s[n*132 + h4*4] = *(const float4*)&H[(long)(n0+n)*HD + h4*4];
    }
    __syncthreads();
    {   // dot products: thread (n = tid>>2, q = tid&3) sums 32 dims
        int n = tid >> 2, q = tid & 3;
        float sp = 0.f, dp = 0.f;
        #pragma unroll
        for (int c = 0; c < 32; ++c) {
            float v = H_s[n*132 + q*32 + c];
            sp += v * as_s[q*32 + c];
            dp += v * ad_s[q*32 + c];
        }
        sp += __shfl_xor(sp, 1); sp += __shfl_xor(sp, 2);
        dp += __shfl_xor(dp, 1); dp += __shfl_xor(dp, 2);
        if (q == 0) {
            int node = n0 + n;
            sdv[0*NN + node] = sp;
            sdv[1*NN + node] = expf(sp);
            sdv[2*NN + node] = expf(0.2f*sp);
            sdv[3*NN + node] = dp;
            sdv[4*NN + node] = expf(dp);
            sdv[5*NN + node] = expf(0.2f*dp);
        }
    }
    {   // transpose -> Htb[h][n0 + half*32 .. +31] bf16
        int h = tid >> 1, half = tid & 1;
        int nb = half * 32;
        unsigned u[16];
        #pragma unroll
        for (int c = 0; c < 16; ++c)
            u[c] = pk2(H_s[(nb + 2*c)*132 + h], H_s[(nb + 2*c + 1)*132 + h]);
        uint4* dst = (uint4*)&Htb[(long)h*NN + n0 + nb];
        dst[0] = make_uint4(u[0], u[1], u[2], u[3]);
        dst[1] = make_uint4(u[4], u[5], u[6], u[7]);
        dst[2] = make_uint4(u[8], u[9], u[10], u[11]);
        dst[3] = make_uint4(u[12], u[13], u[14], u[15]);
    }
}

// ---------------------------------------------------------------------------
// GAT aggregate, MFMA: grid (64 i-tiles of 64, 8 segs of 512 j).
// A-tile (bf16 attention weights) built in LDS from bitmask + factored exps;
// B-fragments read directly from global Htb. C: [seg][N][H] f32 partials.
// ---------------------------------------------------------------------------
__global__ __launch_bounds__(256, 2) void agg_k2(
    const unsigned* __restrict__ adjb, const float* __restrict__ sdv,
    const short* __restrict__ Htb, float* __restrict__ num_part,
    float* __restrict__ den_part)
{
    __shared__ __align__(16) short A_s[64*72];   // [64 i][72 j] bf16
    __shared__ float den_s[64*4];
    const float* s_  = sdv;
    const float* Es_ = sdv + NN;
    const float* es_ = sdv + 2*NN;
    const float* d_  = sdv + 3*NN;
    const float* Ed_ = sdv + 4*NN;
    const float* ed_ = sdv + 5*NN;
    int tid = threadIdx.x;
    int i0  = blockIdx.x * 64;
    int seg = blockIdx.y;
    // builder role: row bi, quarter bq (16 j's)
    int bi = tid >> 2, bq = tid & 3;
    float si  = s_[i0+bi], Esi = Es_[i0+bi], esi = es_[i0+bi];
    // mfma role
    int w = tid >> 6, l = tid & 63, l15 = l & 15, qd = l >> 4;
    f32x4_t acc[8];
    #pragma unroll
    for (int nt = 0; nt < 8; ++nt) acc[nt] = (f32x4_t){0.f,0.f,0.f,0.f};
    float den_acc = 0.f;
    unsigned* Aw = (unsigned*)A_s;

    for (int jc = 0; jc < 8; ++jc) {
        int j0 = seg*512 + jc*64;
        int jb = j0 + bq*16;
        __syncthreads();                    // prev reads done before rewrite
        unsigned word = adjb[(long)(i0+bi)*128 + (jb >> 5)];
        unsigned sh = (bq & 1) * 16;
        #pragma unroll
        for (int g4 = 0; g4 < 4; ++g4) {
            int jj = jb + g4*4;
            float4 d4 = *(const float4*)&d_[jj];
            float4 E4 = *(const float4*)&Ed_[jj];
            float4 e4 = *(const float4*)&ed_[jj];
            const float* dp = (const float*)&d4;
            const float* Ep = (const float*)&E4;
            const float* ep = (const float*)&e4;
            float v[4];
            #pragma unroll
            for (int c = 0; c < 4; ++c) {
                unsigned bit = (word >> (sh + g4*4 + c)) & 1u;
                bool pos = (si + dp[c]) > 0.f;
                float prod = pos ? (Esi * Ep[c]) : (esi * ep[c]);
                v[c] = bit ? prod : 0.f;
                den_acc += v[c];
            }
            Aw[bi*36 + bq*8 + g4*2]     = pk2(v[0], v[1]);
            Aw[bi*36 + bq*8 + g4*2 + 1] = pk2(v[2], v[3]);
        }
        __syncthreads();
        #pragma unroll
        for (int ks = 0; ks < 2; ++ks) {
            int k0 = ks*32 + qd*8;
            short8_t a = *(const short8_t*)&A_s[(w*16 + l15)*72 + k0];
            #pragma unroll
            for (int nt = 0; nt < 8; ++nt) {
                short8_t b = *(const short8_t*)&Htb[(long)(nt*16 + l15)*NN + j0 + k0];
                acc[nt] = __builtin_amdgcn_mfma_f32_16x16x32_bf16(a, b, acc[nt], 0, 0, 0);
            }
        }
    }
    long base = (long)seg*NN*HD;
    #pragma unroll
    for (int nt = 0; nt < 8; ++nt)
        #pragma unroll
        for (int r = 0; r < 4; ++r)
            num_part[base + (long)(i0 + w*16 + qd*4 + r)*HD + nt*16 + l15] = acc[nt][r];
    den_s[bi*4 + bq] = den_acc;
    __syncthreads();
    if (tid < 64)
        den_part[seg*NN + i0 + tid] =
            den_s[tid*4] + den_s[tid*4+1] + den_s[tid*4+2] + den_s[tid*4+3];
}

// ---------------------------------------------------------------------------
__global__ __launch_bounds__(128) void reduce_relu_k(
    const float* __restrict__ num_part, const float* __restrict__ den_part,
    float* __restrict__ G)
{
    int row = blockIdx.x, t = threadIdx.x;
    float n = 0.f, d = 0.f;
    #pragma unroll
    for (int s = 0; s < NSEG; ++s) {
        n += num_part[(long)s*NN*HD + (long)row*HD + t];
        d += den_part[s*NN + row];
    }
    float v = (d > 0.f) ? n/d : 0.f;
    G[(long)row*HD + t] = fmaxf(v, 0.f);
}

__global__ __launch_bounds__(128) void reduce_ln_k(
    const float* __restrict__ num_part, const float* __restrict__ den_part,
    const float* __restrict__ G1, const float* __restrict__ ln_w,
    const float* __restrict__ ln_b, float* __restrict__ HLN)
{
    __shared__ float r1[2], r2[2];
    int row = blockIdx.x, t = threadIdx.x;
    float n = 0.f, d = 0.f;
    #pragma unroll
    for (int s = 0; s < NSEG; ++s) {
        n += num_part[(long)s*NN*HD + (long)row*HD + t];
        d += den_part[s*NN + row];
    }
    float v = (d > 0.f) ? n/d : 0.f;
    v = fmaxf(v, 0.f) + G1[(long)row*HD + t];
    float sum = v, sq = v*v;
    #pragma unroll
    for (int off = 32; off > 0; off >>= 1) {
        sum += __shfl_xor(sum, off);
        sq  += __shfl_xor(sq, off);
    }
    int wid = t >> 6;
    if ((t & 63) == 0) { r1[wid] = sum; r2[wid] = sq; }
    __syncthreads();
    float mu  = (r1[0]+r1[1]) * (1.0f/128.0f);
    float var = (r2[0]+r2[1]) * (1.0f/128.0f) - mu*mu;
    HLN[(long)row*HD + t] = (v - mu) * rsqrtf(var + 1e-5f) * ln_w[t] + ln_b[t];
}

// ---------------------------------------------------------------------------
// u-frag: bf16(bf2f(cand2) * q)
// ---------------------------------------------------------------------------
__device__ __forceinline__ short8_t mulq(short8_t c, const float* qp) {
    union { short8_t s; unsigned u[4]; } r;
    #pragma unroll
    for (int p = 0; p < 4; ++p) {
        float v0 = bf2f(c[2*p])   * qp[2*p];
        float v1 = bf2f(c[2*p+1]) * qp[2*p+1];
        r.u[p] = pk2(v0, v1);
    }
    return r.s;
}

// ---------------------------------------------------------------------------
// fused candidate head, MFMA w/ global-direct B-fragments. 1 block per node.
// ---------------------------------------------------------------------------
__global__ __launch_bounds__(256, 3) void cand_k2(
    const float* __restrict__ cf, const float* __restrict__ am,
    const float* __restrict__ Qb,
    const short* __restrict__ Wc1b, const short* __restrict__ Wc2b,
    const short* __restrict__ Wfu,
    const float* __restrict__ bc1, const float* __restrict__ bc2,
    const float* __restrict__ bs1, const float* __restrict__ Ws2,
    const float* __restrict__ bs2, float* __restrict__ out)
{
    __shared__ __align__(16) short cand_s[64*136];
    __shared__ __align__(16) short cf_bf[64*40];
    __shared__ float cf_s[64*12];
    __shared__ float red_s[64*33];
    __shared__ float b1_s[128], b2_s[128], bs1_s[128], ws2_s[128], q_s[128];

    int tid = threadIdx.x;
    int node = blockIdx.x;

    for (int e = tid; e < NCAND*NCF; e += 256) {
        int c = e / NCF, k = e - c*NCF;
        float v = cf[(long)node*NCAND*NCF + e];
        cf_s[c*12 + k] = v;
        cf_bf[c*40 + k] = f2bf(v);
    }
    for (int e = tid; e < 64*22; e += 256) {   // zero pad k = 10..31
        int c = e / 22, k = 10 + (e - c*22);
        cf_bf[c*40 + k] = 0;
    }
    if (tid < 128) {
        b1_s[tid]  = bc1[tid];
        b2_s[tid]  = bc2[tid];
        bs1_s[tid] = bs1[tid];
        ws2_s[tid] = Ws2[tid];
        q_s[tid]   = Qb[(long)node*HD + tid];
    }
    __syncthreads();

    int w = tid >> 6, l = tid & 63, l15 = l & 15, qd = l >> 4;
    int mt0 = (w >> 1) * 2;
    int nt0 = (w & 1) * 4;

    // ---- GEMM1: cand1 = gelu(cf @ Wc1^T + bc1), K=32 (zero-padded) --------
    {
        f32x4_t a1[2][4];
        #pragma unroll
        for (int im = 0; im < 2; ++im)
            #pragma unroll
            for (int in = 0; in < 4; ++in) a1[im][in] = (f32x4_t){0.f,0.f,0.f,0.f};
        int k0 = qd*8;
        short8_t fa0 = *(const short8_t*)&cf_bf[(mt0*16 + l15)*40 + k0];
        short8_t fa1 = *(const short8_t*)&cf_bf[((mt0+1)*16 + l15)*40 + k0];
        #pragma unroll
        for (int in = 0; in < 4; ++in) {
            short8_t b = *(const short8_t*)&Wc1b[((nt0+in)*16 + l15)*32 + k0];
            a1[0][in] = __builtin_amdgcn_mfma_f32_16x16x32_bf16(fa0, b, a1[0][in], 0,0,0);
            a1[1][in] = __builtin_amdgcn_mfma_f32_16x16x32_bf16(fa1, b, a1[1][in], 0,0,0);
        }
        #pragma unroll
        for (int im = 0; im < 2; ++im)
            #pragma unroll
            for (int in = 0; in < 4; ++in)
                #pragma unroll
                for (int r = 0; r < 4; ++r) {
                    int c = (mt0+im)*16 + qd*4 + r;
                    int n = (nt0+in)*16 + l15;
                    cand_s[c*136 + n] = f2bf(gelu_f(a1[im][in][r] + b1_s[n]));
                }
    }
    __syncthreads();

    // ---- GEMM2: cand2 = gelu(cand1 @ Wc2^T + bc2) -------------------------
    f32x4_t acc[2][4];
    #pragma unroll
    for (int im = 0; im < 2; ++im)
        #pragma unroll
        for (int in = 0; in < 4; ++in) acc[im][in] = (f32x4_t){0.f,0.f,0.f,0.f};
    #pragma unroll
    for (int kc = 0; kc < 4; ++kc) {
        int k0 = kc*32 + qd*8;
        short8_t a0 = *(const short8_t*)&cand_s[(mt0*16 + l15)*136 + k0];
        short8_t a1 = *(const short8_t*)&cand_s[((mt0+1)*16 + l15)*136 + k0];
        #pragma unroll
        for (int in = 0; in < 4; ++in) {
            short8_t b = *(const short8_t*)&Wc2b[((nt0+in)*16 + l15)*128 + k0];
            acc[0][in] = __builtin_amdgcn_mfma_f32_16x16x32_bf16(a0, b, acc[0][in], 0,0,0);
            acc[1][in] = __builtin_amdgcn_mfma_f32_16x16x32_bf16(a1, b, acc[1][in], 0,0,0);
        }
    }
    __syncthreads();           // all reads of cand1 complete
    #pragma unroll
    for (int im = 0; im < 2; ++im)
        #pragma unroll
        for (int in = 0; in < 4; ++in)
            #pragma unroll
            for (int r = 0; r < 4; ++r) {
                int c = (mt0+im)*16 + qd*4 + r;
                int n = (nt0+in)*16 + l15;
                cand_s[c*136 + n] = f2bf(gelu_f(acc[im][in][r] + b2_s[n]));
            }
    __syncthreads();

    // ---- GEMM3: score = [cand2 | q*cand2] @ Wfu^T (K=256) -----------------
    #pragma unroll
    for (int im = 0; im < 2; ++im)
        #pragma unroll
        for (int in = 0; in < 4; ++in) acc[im][in] = (f32x4_t){0.f,0.f,0.f,0.f};
    #pragma unroll
    for (int kc = 0; kc < 8; ++kc) {
        int k0 = kc*32 + qd*8;
        short8_t a0, a1;
        if (kc < 4) {
            a0 = *(const short8_t*)&cand_s[(mt0*16 + l15)*136 + k0];
            a1 = *(const short8_t*)&cand_s[((mt0+1)*16 + l15)*136 + k0];
        } else {
            int kk = k0 - 128;
            short8_t c0 = *(const short8_t*)&cand_s[(mt0*16 + l15)*136 + kk];
            short8_t c1 = *(const short8_t*)&cand_s[((mt0+1)*16 + l15)*136 + kk];
            a0 = mulq(c0, &q_s[kk]);
            a1 = mulq(c1, &q_s[kk]);
        }
        #pragma unroll
        for (int in = 0; in < 4; ++in) {
            short8_t b = *(const short8_t*)&Wfu[((nt0+in)*16 + l15)*256 + k0];
            acc[0][in] = __builtin_amdgcn_mfma_f32_16x16x32_bf16(a0, b, acc[0][in], 0,0,0);
            acc[1][in] = __builtin_amdgcn_mfma_f32_16x16x32_bf16(a1, b, acc[1][in], 0,0,0);
        }
    }

    // ---- epilogue ---------------------------------------------------------
    #pragma unroll
    for (int im = 0; im < 2; ++im)
        #pragma unroll
        for (int r = 0; r < 4; ++r) {
            float p = 0.f;
            #pragma unroll
            for (int in = 0; in < 4; ++in) {
                int n = (nt0+in)*16 + l15;
                p += gelu_f(acc[im][in][r] + bs1_s[n]) * ws2_s[n];
            }
            int c = (mt0+im)*16 + qd*4 + r;
            red_s[c*33 + (w&1)*16 + l15] = p;
        }
    __syncthreads();

    if (tid < 64) {
        int c = tid;
        float lg = bs2[0];
        #pragma unroll
        for (int s = 0; s < 32; ++s) lg += red_s[c*33 + s];
        const float* r = &cf_s[c*12];
        lg += 20.0f*r[0] + 4.0f*r[4] + 1.5f*r[5] + 1.5f*r[1] - 1.5f*r[2]
            + 1.2f*r[6] + 2.5f*r[7] + 1.6f*r[8] + 1.2f*r[9];
        float m = am[(long)node*NCAND + c];
        float tot = m;
        #pragma unroll
        for (int off = 32; off > 0; off >>= 1) tot += __shfl_xor(tot, off);
        if (c == 0 && tot <= 0.f) m = 1.0f;
        out[(long)node*NCAND + c] = (m > 0.f) ? lg : NEGV;
    }
}

// ---------------------------------------------------------------------------
extern "C" void kernel_launch(void* const* d_in, const int* in_sizes, int n_in,
                              void* d_out, int out_size, void* d_ws, size_t ws_size,
                              hipStream_t stream)
{
    const float* X   = (const float*)d_in[0];
    const float* CF  = (const float*)d_in[1];
    const int*   ADJ = (const int*)d_in[2];
    const float* AM  = (const float*)d_in[3];
    const float* W1  = (const float*)d_in[4];
    const float* A1S = (const float*)d_in[5];
    const float* A1D = (const float*)d_in[6];
    const float* W2  = (const float*)d_in[7];
    const float* A2S = (const float*)d_in[8];
    const float* A2D = (const float*)d_in[9];
    const float* LNW = (const float*)d_in[10];
    const float* LNB = (const float*)d_in[11];
    const float* WC1 = (const float*)d_in[12];
    const float* BC1 = (const float*)d_in[13];
    const float* WC2 = (const float*)d_in[14];
    const float* BC2 = (const float*)d_in[15];
    const float* WQ  = (const float*)d_in[16];
    const float* BQ  = (const float*)d_in[17];
    const float* WS1 = (const float*)d_in[18];
    const float* BS1 = (const float*)d_in[19];
    const float* WS2 = (const float*)d_in[20];
    const float* BS2 = (const float*)d_in[21];
    float* OUT = (float*)d_out;

    float* ws = (float*)d_ws;
    float*    Abuf = ws;                               // H1 / H2 / Qb (524288)
    float*    G1   = ws + 524288;
    float*    HLN  = ws + 1048576;
    float*    sdv  = ws + 1572864;                     // 24576
    float*    denp = ws + 1597440;                     // 32768
    short*    Htb  = (short*)(ws + 1630208);           // 524288 shorts
    unsigned* adjb = (unsigned*)(ws + 1892352);        // 524288 words
    short*    Wc1b = (short*)(ws + 2416640);           // 4096 shorts
    short*    Wc2b = (short*)(ws + 2418688);           // 16384 shorts
    short*    Wfu  = (short*)(ws + 2426880);           // 32768 shorts
    float*    nump = ws + 2443264;                     // 4194304 -> end 6637568

    const int SG_SMEM = (128*129 + 16*128 + 128) * 4;

    // one-time preps
    wprep_k<<<64, 256, 0, stream>>>(WC1, WC2, WS1, Wc1b, Wc2b, Wfu);
    pack_k<<<2048, 256, 0, stream>>>(ADJ, adjb);

    // GAT layer 1
    small_gemm_k<64><<<256, 256, SG_SMEM, stream>>>(X, W1, nullptr, Abuf);
    prep_k<<<64, 256, 0, stream>>>(Abuf, A1S, A1D, sdv, Htb);
    agg_k2<<<dim3(64, NSEG), 256, 0, stream>>>(adjb, sdv, Htb, nump, denp);
    reduce_relu_k<<<NN, 128, 0, stream>>>(nump, denp, G1);

    // GAT layer 2 + residual + LN
    small_gemm_k<128><<<256, 256, SG_SMEM, stream>>>(G1, W2, nullptr, Abuf);
    prep_k<<<64, 256, 0, stream>>>(Abuf, A2S, A2D, sdv, Htb);
    agg_k2<<<dim3(64, NSEG), 256, 0, stream>>>(adjb, sdv, Htb, nump, denp);
    reduce_ln_k<<<NN, 128, 0, stream>>>(nump, denp, G1, LNW, LNB, HLN);

    // query projection (Qb aliases Abuf — H2 dead after prep_k)
    small_gemm_k<128><<<256, 256, SG_SMEM, stream>>>(HLN, WQ, BQ, Abuf);

    // fused candidate head
    cand_k2<<<NN, 256, 0, stream>>>(CF, AM, Abuf, Wc1b, Wc2b, Wfu,
                                    BC1, BC2, BS1, WS2, BS2, OUT);
}

// Round 4
// 421.571 us; speedup vs baseline: 2.4296x; 1.0291x over previous
//
#include <hip/hip_runtime.h>
#include <hip/hip_bf16.h>
#include <math.h>

#define NN 4096
#define HD 128
#define NCAND 64
#define NCF 10
#define NSEG 8
#define NEGV (-1000000000.0f)

typedef __attribute__((ext_vector_type(8))) short short8_t;
typedef __attribute__((ext_vector_type(4))) float f32x4_t;

// ---- bf16 helpers ---------------------------------------------------------
__device__ __forceinline__ short f2bf(float f) {
    union { float f; unsigned u; } v; v.f = f;
    unsigned r = (v.u + 0x7FFFu + ((v.u >> 16) & 1u)) >> 16;
    return (short)r;
}
__device__ __forceinline__ float bf2f(short s) {
    union { unsigned u; float f; } v; v.u = ((unsigned)(unsigned short)s) << 16;
    return v.f;
}
__device__ __forceinline__ unsigned pk2(float a, float b) {
    union { __hip_bfloat162 h; unsigned u; } v;
    v.h = __float22bfloat162_rn(make_float2(a, b));
    return v.u;
}

// fast gelu (tanh form)
__device__ __forceinline__ float gelu_f(float x) {
    const float A = 2.3022082f, B = 0.1029432f;
    float x2 = x * x;
    float z2 = x * (A + B * x2);
    float e  = __builtin_amdgcn_exp2f(z2);
    float r  = __builtin_amdgcn_rcpf(e + 1.0f);
    return x - x * r;
}

// ---------------------------------------------------------------------------
// pack adjacency into bitmask
// ---------------------------------------------------------------------------
__global__ __launch_bounds__(256) void pack_k(
    const int* __restrict__ adj, unsigned* __restrict__ adjb)
{
    long g = (long)blockIdx.x * 256 + threadIdx.x;   // 524288 words
    const int4* p = (const int4*)adj + g * 8;
    unsigned w = 0;
    #pragma unroll
    for (int e = 0; e < 8; ++e) {
        int4 v = p[e];
        w |= (unsigned)(v.x != 0) << (e*4 + 0);
        w |= (unsigned)(v.y != 0) << (e*4 + 1);
        w |= (unsigned)(v.z != 0) << (e*4 + 2);
        w |= (unsigned)(v.w != 0) << (e*4 + 3);
    }
    adjb[g] = w;
}

// ---------------------------------------------------------------------------
// weight prep: all bf16 conversions
// ---------------------------------------------------------------------------
__global__ __launch_bounds__(256) void wprep_k(
    const float* __restrict__ Wc1, const float* __restrict__ Wc2,
    const float* __restrict__ Ws1, const float* __restrict__ W1,
    const float* __restrict__ W2, const float* __restrict__ Wq,
    short* __restrict__ Wc1b, short* __restrict__ Wc2b, short* __restrict__ Wfu,
    short* __restrict__ W1b, short* __restrict__ W2b, short* __restrict__ Wqb)
{
    int g = blockIdx.x * 256 + threadIdx.x;
    int tot = gridDim.x * 256;
    for (int e = g; e < 128*32; e += tot) {
        int t = e >> 5, k = e & 31;
        Wc1b[e] = (k < NCF) ? f2bf(Wc1[t*NCF + k]) : (short)0;
    }
    for (int e = g; e < 128*128; e += tot) Wc2b[e] = f2bf(Wc2[e]);
    for (int e = g; e < 128*256; e += tot) {
        int h = e >> 8, j = e & 255;
        float v = (j < 128) ? Ws1[h*256 + 128 + j] : Ws1[h*256 + (j - 128)];
        Wfu[e] = f2bf(v);
    }
    for (int e = g; e < 128*64;  e += tot) W1b[e] = f2bf(W1[e]);
    for (int e = g; e < 128*128; e += tot) W2b[e] = f2bf(W2[e]);
    for (int e = g; e < 128*128; e += tot) Wqb[e] = f2bf(Wq[e]);
}

// ---------------------------------------------------------------------------
// fused input transform: H = in @ W^T (bf16 MFMA).
// MODE 0: keep H in LDS, emit attention scalars sdv + transposed bf16 Htb.
// MODE 1: write H + bias to global f32 (query projection).
// 64 rows per block, grid 64 (MODE layers) / 64 (qproj).
// ---------------------------------------------------------------------------
template<int K, int MODE>
__global__ __launch_bounds__(256) void gatin_k(
    const float* __restrict__ in, const short* __restrict__ Wb,
    const float* __restrict__ bias,
    const float* __restrict__ a_s, const float* __restrict__ a_d,
    float* __restrict__ sdv, short* __restrict__ Htb,
    float* __restrict__ outq)
{
    constexpr int AS = K + 8;                     // short stride (16B aligned)
    __shared__ __align__(16) short A_s[64*AS];
    __shared__ float H_s[64*133];
    __shared__ float aux_s[256];
    int tid = threadIdx.x;
    int n0 = blockIdx.x * 64;

    {   // stage A rows as bf16
        const float2* src = (const float2*)(in + (long)n0*K);
        unsigned* aw = (unsigned*)A_s;
        for (int e = tid; e < 64*(K/2); e += 256) {
            int row = e / (K/2), kp = e - row*(K/2);
            float2 v = src[e];
            aw[row*(AS/2) + kp] = pk2(v.x, v.y);
        }
    }
    if (MODE == 0) {
        if (tid < 128) { aux_s[tid] = a_s[tid]; aux_s[128+tid] = a_d[tid]; }
    } else {
        if (tid < 128) aux_s[tid] = bias[tid];
    }
    __syncthreads();

    int w = tid >> 6, l = tid & 63, l15 = l & 15, qd = l >> 4;
    int mt0 = (w >> 1) * 2, nt0 = (w & 1) * 4;
    f32x4_t acc[2][4];
    #pragma unroll
    for (int im = 0; im < 2; ++im)
        #pragma unroll
        for (int in_ = 0; in_ < 4; ++in_) acc[im][in_] = (f32x4_t){0.f,0.f,0.f,0.f};
    #pragma unroll
    for (int kc = 0; kc < K/32; ++kc) {
        int k0 = kc*32 + qd*8;
        short8_t a0 = *(const short8_t*)&A_s[(mt0*16 + l15)*AS + k0];
        short8_t a1 = *(const short8_t*)&A_s[((mt0+1)*16 + l15)*AS + k0];
        #pragma unroll
        for (int in_ = 0; in_ < 4; ++in_) {
            short8_t b = *(const short8_t*)&Wb[((nt0+in_)*16 + l15)*K + k0];
            acc[0][in_] = __builtin_amdgcn_mfma_f32_16x16x32_bf16(a0, b, acc[0][in_], 0,0,0);
            acc[1][in_] = __builtin_amdgcn_mfma_f32_16x16x32_bf16(a1, b, acc[1][in_], 0,0,0);
        }
    }

    if (MODE == 1) {
        #pragma unroll
        for (int im = 0; im < 2; ++im)
            #pragma unroll
            for (int in_ = 0; in_ < 4; ++in_)
                #pragma unroll
                for (int r = 0; r < 4; ++r) {
                    int m = (mt0+im)*16 + qd*4 + r;
                    int n = (nt0+in_)*16 + l15;
                    outq[(long)(n0+m)*HD + n] = acc[im][in_][r] + aux_s[n];
                }
        return;
    }

    // MODE 0: H into LDS
    #pragma unroll
    for (int im = 0; im < 2; ++im)
        #pragma unroll
        for (int in_ = 0; in_ < 4; ++in_)
            #pragma unroll
            for (int r = 0; r < 4; ++r) {
                int m = (mt0+im)*16 + qd*4 + r;
                int n = (nt0+in_)*16 + l15;
                H_s[m*133 + n] = acc[im][in_][r];
            }
    __syncthreads();

    {   // attention scalars: thread (n = tid>>2, q = tid&3) sums 32 dims
        int n = tid >> 2, q = tid & 3;
        float sp = 0.f, dp = 0.f;
        #pragma unroll
        for (int c = 0; c < 32; ++c) {
            float v = H_s[n*133 + q*32 + c];
            sp += v * aux_s[q*32 + c];
            dp += v * aux_s[128 + q*32 + c];
        }
        sp += __shfl_xor(sp, 1); sp += __shfl_xor(sp, 2);
        dp += __shfl_xor(dp, 1); dp += __shfl_xor(dp, 2);
        if (q == 0) {
            int node = n0 + n;
            sdv[0*NN + node] = sp;
            sdv[1*NN + node] = expf(sp);
            sdv[2*NN + node] = expf(0.2f*sp);
            sdv[3*NN + node] = dp;
            sdv[4*NN + node] = expf(dp);
            sdv[5*NN + node] = expf(0.2f*dp);
        }
    }
    {   // transpose -> Htb[h][n0 + half*32 .. +31] bf16
        int h = tid >> 1, half = tid & 1;
        int nb = half * 32;
        unsigned u[16];
        #pragma unroll
        for (int c = 0; c < 16; ++c)
            u[c] = pk2(H_s[(nb + 2*c)*133 + h], H_s[(nb + 2*c + 1)*133 + h]);
        uint4* dst = (uint4*)&Htb[(long)h*NN + n0 + nb];
        dst[0] = make_uint4(u[0], u[1], u[2], u[3]);
        dst[1] = make_uint4(u[4], u[5], u[6], u[7]);
        dst[2] = make_uint4(u[8], u[9], u[10], u[11]);
        dst[3] = make_uint4(u[12], u[13], u[14], u[15]);
    }
}

// ---------------------------------------------------------------------------
// GAT aggregate, MFMA (unchanged from round 3)
// ---------------------------------------------------------------------------
__global__ __launch_bounds__(256, 2) void agg_k2(
    const unsigned* __restrict__ adjb, const float* __restrict__ sdv,
    const short* __restrict__ Htb, float* __restrict__ num_part,
    float* __restrict__ den_part)
{
    __shared__ __align__(16) short A_s[64*72];
    __shared__ float den_s[64*4];
    const float* s_  = sdv;
    const float* Es_ = sdv + NN;
    const float* es_ = sdv + 2*NN;
    const float* d_  = sdv + 3*NN;
    const float* Ed_ = sdv + 4*NN;
    const float* ed_ = sdv + 5*NN;
    int tid = threadIdx.x;
    int i0  = blockIdx.x * 64;
    int seg = blockIdx.y;
    int bi = tid >> 2, bq = tid & 3;
    float si  = s_[i0+bi], Esi = Es_[i0+bi], esi = es_[i0+bi];
    int w = tid >> 6, l = tid & 63, l15 = l & 15, qd = l >> 4;
    f32x4_t acc[8];
    #pragma unroll
    for (int nt = 0; nt < 8; ++nt) acc[nt] = (f32x4_t){0.f,0.f,0.f,0.f};
    float den_acc = 0.f;
    unsigned* Aw = (unsigned*)A_s;

    for (int jc = 0; jc < 8; ++jc) {
        int j0 = seg*512 + jc*64;
        int jb = j0 + bq*16;
        __syncthreads();
        unsigned word = adjb[(long)(i0+bi)*128 + (jb >> 5)];
        unsigned sh = (bq & 1) * 16;
        #pragma unroll
        for (int g4 = 0; g4 < 4; ++g4) {
            int jj = jb + g4*4;
            float4 d4 = *(const float4*)&d_[jj];
            float4 E4 = *(const float4*)&Ed_[jj];
            float4 e4 = *(const float4*)&ed_[jj];
            const float* dp = (const float*)&d4;
            const float* Ep = (const float*)&E4;
            const float* ep = (const float*)&e4;
            float v[4];
            #pragma unroll
            for (int c = 0; c < 4; ++c) {
                unsigned bit = (word >> (sh + g4*4 + c)) & 1u;
                bool pos = (si + dp[c]) > 0.f;
                float prod = pos ? (Esi * Ep[c]) : (esi * ep[c]);
                v[c] = bit ? prod : 0.f;
                den_acc += v[c];
            }
            Aw[bi*36 + bq*8 + g4*2]     = pk2(v[0], v[1]);
            Aw[bi*36 + bq*8 + g4*2 + 1] = pk2(v[2], v[3]);
        }
        __syncthreads();
        #pragma unroll
        for (int ks = 0; ks < 2; ++ks) {
            int k0 = ks*32 + qd*8;
            short8_t a = *(const short8_t*)&A_s[(w*16 + l15)*72 + k0];
            #pragma unroll
            for (int nt = 0; nt < 8; ++nt) {
                short8_t b = *(const short8_t*)&Htb[(long)(nt*16 + l15)*NN + j0 + k0];
                acc[nt] = __builtin_amdgcn_mfma_f32_16x16x32_bf16(a, b, acc[nt], 0, 0, 0);
            }
        }
    }
    long base = (long)seg*NN*HD;
    #pragma unroll
    for (int nt = 0; nt < 8; ++nt)
        #pragma unroll
        for (int r = 0; r < 4; ++r)
            num_part[base + (long)(i0 + w*16 + qd*4 + r)*HD + nt*16 + l15] = acc[nt][r];
    den_s[bi*4 + bq] = den_acc;
    __syncthreads();
    if (tid < 64)
        den_part[seg*NN + i0 + tid] =
            den_s[tid*4] + den_s[tid*4+1] + den_s[tid*4+2] + den_s[tid*4+3];
}

// ---------------------------------------------------------------------------
__global__ __launch_bounds__(128) void reduce_relu_k(
    const float* __restrict__ num_part, const float* __restrict__ den_part,
    float* __restrict__ G)
{
    int row = blockIdx.x, t = threadIdx.x;
    float n = 0.f, d = 0.f;
    #pragma unroll
    for (int s = 0; s < NSEG; ++s) {
        n += num_part[(long)s*NN*HD + (long)row*HD + t];
        d += den_part[s*NN + row];
    }
    float v = (d > 0.f) ? n/d : 0.f;
    G[(long)row*HD + t] = fmaxf(v, 0.f);
}

__global__ __launch_bounds__(128) void reduce_ln_k(
    const float* __restrict__ num_part, const float* __restrict__ den_part,
    const float* __restrict__ G1, const float* __restrict__ ln_w,
    const float* __restrict__ ln_b, float* __restrict__ HLN)
{
    __shared__ float r1[2], r2[2];
    int row = blockIdx.x, t = threadIdx.x;
    float n = 0.f, d = 0.f;
    #pragma unroll
    for (int s = 0; s < NSEG; ++s) {
        n += num_part[(long)s*NN*HD + (long)row*HD + t];
        d += den_part[s*NN + row];
    }
    float v = (d > 0.f) ? n/d : 0.f;
    v = fmaxf(v, 0.f) + G1[(long)row*HD + t];
    float sum = v, sq = v*v;
    #pragma unroll
    for (int off = 32; off > 0; off >>= 1) {
        sum += __shfl_xor(sum, off);
        sq  += __shfl_xor(sq, off);
    }
    int wid = t >> 6;
    if ((t & 63) == 0) { r1[wid] = sum; r2[wid] = sq; }
    __syncthreads();
    float mu  = (r1[0]+r1[1]) * (1.0f/128.0f);
    float var = (r2[0]+r2[1]) * (1.0f/128.0f) - mu*mu;
    HLN[(long)row*HD + t] = (v - mu) * rsqrtf(var + 1e-5f) * ln_w[t] + ln_b[t];
}

// u-frag: bf16(bf2f(cand2) * q)
__device__ __forceinline__ short8_t mulq(short8_t c, const float* qp) {
    union { short8_t s; unsigned u[4]; } r;
    #pragma unroll
    for (int p = 0; p < 4; ++p) {
        float v0 = bf2f(c[2*p])   * qp[2*p];
        float v1 = bf2f(c[2*p+1]) * qp[2*p+1];
        r.u[p] = pk2(v0, v1);
    }
    return r.s;
}

// ---------------------------------------------------------------------------
// fused candidate head v3: ~21 KB LDS -> 5 blocks/CU. A-frags for GEMM1
// direct from global; epilogue reduced via shuffles.
// ---------------------------------------------------------------------------
__global__ __launch_bounds__(256, 5) void cand_k3(
    const float* __restrict__ cf, const float* __restrict__ am,
    const float* __restrict__ Qb,
    const short* __restrict__ Wc1b, const short* __restrict__ Wc2b,
    const short* __restrict__ Wfu,
    const float* __restrict__ bc1, const float* __restrict__ bc2,
    const float* __restrict__ bs1, const float* __restrict__ Ws2,
    const float* __restrict__ bs2, float* __restrict__ out)
{
    __shared__ __align__(16) short cand_s[64*136];
    __shared__ float b1_s[128], b2_s[128], bs1_s[128], ws2_s[128], q_s[128];
    __shared__ float red_s[64*2];

    int tid = threadIdx.x;
    int node = blockIdx.x;
    const float* cfn = cf + (long)node*NCAND*NCF;

    if (tid < 128) {
        b1_s[tid]  = bc1[tid];
        b2_s[tid]  = bc2[tid];
        bs1_s[tid] = bs1[tid];
        ws2_s[tid] = Ws2[tid];
        q_s[tid]   = Qb[(long)node*HD + tid];
    }

    int w = tid >> 6, l = tid & 63, l15 = l & 15, qd = l >> 4;
    int mt0 = (w >> 1) * 2, nt0 = (w & 1) * 4;

    // ---- GEMM1 A-frags direct from global cf ------------------------------
    short8_t fa[2];
    #pragma unroll
    for (int im = 0; im < 2; ++im) {
        int c = (mt0+im)*16 + l15;
        union { short8_t s; unsigned u[4]; } r;
        if (qd == 0) {
            float4 x = *(const float4*)&cfn[c*10];
            float4 y = *(const float4*)&cfn[c*10 + 4];
            r.u[0] = pk2(x.x, x.y); r.u[1] = pk2(x.z, x.w);
            r.u[2] = pk2(y.x, y.y); r.u[3] = pk2(y.z, y.w);
        } else if (qd == 1) {
            float2 x = *(const float2*)&cfn[c*10 + 8];
            r.u[0] = pk2(x.x, x.y); r.u[1] = 0; r.u[2] = 0; r.u[3] = 0;
        } else {
            r.u[0] = r.u[1] = r.u[2] = r.u[3] = 0;
        }
        fa[im] = r.s;
    }
    __syncthreads();   // staging visible

    f32x4_t acc[2][4];
    #pragma unroll
    for (int im = 0; im < 2; ++im)
        #pragma unroll
        for (int in_ = 0; in_ < 4; ++in_) acc[im][in_] = (f32x4_t){0.f,0.f,0.f,0.f};
    #pragma unroll
    for (int in_ = 0; in_ < 4; ++in_) {
        short8_t b = *(const short8_t*)&Wc1b[((nt0+in_)*16 + l15)*32 + qd*8];
        acc[0][in_] = __builtin_amdgcn_mfma_f32_16x16x32_bf16(fa[0], b, acc[0][in_], 0,0,0);
        acc[1][in_] = __builtin_amdgcn_mfma_f32_16x16x32_bf16(fa[1], b, acc[1][in_], 0,0,0);
    }
    #pragma unroll
    for (int im = 0; im < 2; ++im)
        #pragma unroll
        for (int in_ = 0; in_ < 4; ++in_)
            #pragma unroll
            for (int r = 0; r < 4; ++r) {
                int c = (mt0+im)*16 + qd*4 + r;
                int n = (nt0+in_)*16 + l15;
                cand_s[c*136 + n] = f2bf(gelu_f(acc[im][in_][r] + b1_s[n]));
            }
    __syncthreads();

    // ---- GEMM2: cand2 = gelu(cand1 @ Wc2^T + bc2) -------------------------
    #pragma unroll
    for (int im = 0; im < 2; ++im)
        #pragma unroll
        for (int in_ = 0; in_ < 4; ++in_) acc[im][in_] = (f32x4_t){0.f,0.f,0.f,0.f};
    #pragma unroll
    for (int kc = 0; kc < 4; ++kc) {
        int k0 = kc*32 + qd*8;
        short8_t a0 = *(const short8_t*)&cand_s[(mt0*16 + l15)*136 + k0];
        short8_t a1 = *(const short8_t*)&cand_s[((mt0+1)*16 + l15)*136 + k0];
        #pragma unroll
        for (int in_ = 0; in_ < 4; ++in_) {
            short8_t b = *(const short8_t*)&Wc2b[((nt0+in_)*16 + l15)*128 + k0];
            acc[0][in_] = __builtin_amdgcn_mfma_f32_16x16x32_bf16(a0, b, acc[0][in_], 0,0,0);
            acc[1][in_] = __builtin_amdgcn_mfma_f32_16x16x32_bf16(a1, b, acc[1][in_], 0,0,0);
        }
    }
    __syncthreads();   // cand1 reads complete
    #pragma unroll
    for (int im = 0; im < 2; ++im)
        #pragma unroll
        for (int in_ = 0; in_ < 4; ++in_)
            #pragma unroll
            for (int r = 0; r < 4; ++r) {
                int c = (mt0+im)*16 + qd*4 + r;
                int n = (nt0+in_)*16 + l15;
                cand_s[c*136 + n] = f2bf(gelu_f(acc[im][in_][r] + b2_s[n]));
            }
    __syncthreads();

    // ---- GEMM3: score = [cand2 | q*cand2] @ Wfu^T (K=256 folded) ----------
    #pragma unroll
    for (int im = 0; im < 2; ++im)
        #pragma unroll
        for (int in_ = 0; in_ < 4; ++in_) acc[im][in_] = (f32x4_t){0.f,0.f,0.f,0.f};
    #pragma unroll
    for (int kc = 0; kc < 4; ++kc) {
        int k0 = kc*32 + qd*8;
        short8_t a0 = *(const short8_t*)&cand_s[(mt0*16 + l15)*136 + k0];
        short8_t a1 = *(const short8_t*)&cand_s[((mt0+1)*16 + l15)*136 + k0];
        #pragma unroll
        for (int in_ = 0; in_ < 4; ++in_) {
            short8_t b = *(const short8_t*)&Wfu[((nt0+in_)*16 + l15)*256 + k0];
            acc[0][in_] = __builtin_amdgcn_mfma_f32_16x16x32_bf16(a0, b, acc[0][in_], 0,0,0);
            acc[1][in_] = __builtin_amdgcn_mfma_f32_16x16x32_bf16(a1, b, acc[1][in_], 0,0,0);
        }
        short8_t aq0 = mulq(a0, &q_s[k0]);
        short8_t aq1 = mulq(a1, &q_s[k0]);
        #pragma unroll
        for (int in_ = 0; in_ < 4; ++in_) {
            short8_t b = *(const short8_t*)&Wfu[((nt0+in_)*16 + l15)*256 + 128 + k0];
            acc[0][in_] = __builtin_amdgcn_mfma_f32_16x16x32_bf16(aq0, b, acc[0][in_], 0,0,0);
            acc[1][in_] = __builtin_amdgcn_mfma_f32_16x16x32_bf16(aq1, b, acc[1][in_], 0,0,0);
        }
    }

    // ---- epilogue: shuffle-reduce across l15 ------------------------------
    #pragma unroll
    for (int im = 0; im < 2; ++im)
        #pragma unroll
        for (int r = 0; r < 4; ++r) {
            float p = 0.f;
            #pragma unroll
            for (int in_ = 0; in_ < 4; ++in_) {
                int n = (nt0+in_)*16 + l15;
                p += gelu_f(acc[im][in_][r] + bs1_s[n]) * ws2_s[n];
            }
            p += __shfl_xor(p, 1); p += __shfl_xor(p, 2);
            p += __shfl_xor(p, 4); p += __shfl_xor(p, 8);
            if (l15 == 0)
                red_s[((mt0+im)*16 + qd*4 + r)*2 + (w & 1)] = p;
        }
    __syncthreads();

    if (tid < 64) {
        int c = tid;
        float lg = red_s[c*2] + red_s[c*2+1] + bs2[0];
        const float* r = cfn + c*10;
        lg += 20.0f*r[0] + 4.0f*r[4] + 1.5f*r[5] + 1.5f*r[1] - 1.5f*r[2]
            + 1.2f*r[6] + 2.5f*r[7] + 1.6f*r[8] + 1.2f*r[9];
        float m = am[(long)node*NCAND + c];
        float tot = m;
        #pragma unroll
        for (int off = 32; off > 0; off >>= 1) tot += __shfl_xor(tot, off);
        if (c == 0 && tot <= 0.f) m = 1.0f;
        out[(long)node*NCAND + c] = (m > 0.f) ? lg : NEGV;
    }
}

// ---------------------------------------------------------------------------
extern "C" void kernel_launch(void* const* d_in, const int* in_sizes, int n_in,
                              void* d_out, int out_size, void* d_ws, size_t ws_size,
                              hipStream_t stream)
{
    const float* X   = (const float*)d_in[0];
    const float* CF  = (const float*)d_in[1];
    const int*   ADJ = (const int*)d_in[2];
    const float* AM  = (const float*)d_in[3];
    const float* W1  = (const float*)d_in[4];
    const float* A1S = (const float*)d_in[5];
    const float* A1D = (const float*)d_in[6];
    const float* W2  = (const float*)d_in[7];
    const float* A2S = (const float*)d_in[8];
    const float* A2D = (const float*)d_in[9];
    const float* LNW = (const float*)d_in[10];
    const float* LNB = (const float*)d_in[11];
    const float* WC1 = (const float*)d_in[12];
    const float* BC1 = (const float*)d_in[13];
    const float* WC2 = (const float*)d_in[14];
    const float* BC2 = (const float*)d_in[15];
    const float* WQ  = (const float*)d_in[16];
    const float* BQ  = (const float*)d_in[17];
    const float* WS1 = (const float*)d_in[18];
    const float* BS1 = (const float*)d_in[19];
    const float* WS2 = (const float*)d_in[20];
    const float* BS2 = (const float*)d_in[21];
    float* OUT = (float*)d_out;

    float* ws = (float*)d_ws;
    float*    G1   = ws;                               // 524288
    float*    HLN  = ws + 524288;                      // 524288
    float*    Qb   = ws + 1048576;                     // 524288
    float*    sdv  = ws + 1572864;                     // 24576
    float*    denp = ws + 1597440;                     // 32768
    short*    Htb  = (short*)(ws + 1630208);           // 524288 shorts
    unsigned* adjb = (unsigned*)(ws + 1892352);        // 524288 words
    short*    Wc1b = (short*)(ws + 2416640);           // 4096 shorts
    short*    Wc2b = (short*)(ws + 2418688);           // 16384 shorts
    short*    Wfu  = (short*)(ws + 2426880);           // 32768 shorts
    short*    W1b  = (short*)(ws + 2443264);           // 8192 shorts
    short*    W2b  = (short*)(ws + 2447360);           // 16384 shorts
    short*    Wqb  = (short*)(ws + 2455552);           // 16384 shorts
    float*    nump = ws + 2463744;                     // 4194304

    // one-time preps
    wprep_k<<<64, 256, 0, stream>>>(WC1, WC2, WS1, W1, W2, WQ,
                                    Wc1b, Wc2b, Wfu, W1b, W2b, Wqb);
    pack_k<<<2048, 256, 0, stream>>>(ADJ, adjb);

    // GAT layer 1 (fused gemm + scalars + transpose)
    gatin_k<64, 0><<<64, 256, 0, stream>>>(X, W1b, nullptr, A1S, A1D, sdv, Htb, nullptr);
    agg_k2<<<dim3(64, NSEG), 256, 0, stream>>>(adjb, sdv, Htb, nump, denp);
    reduce_relu_k<<<NN, 128, 0, stream>>>(nump, denp, G1);

    // GAT layer 2 + residual + LN
    gatin_k<128, 0><<<64, 256, 0, stream>>>(G1, W2b, nullptr, A2S, A2D, sdv, Htb, nullptr);
    agg_k2<<<dim3(64, NSEG), 256, 0, stream>>>(adjb, sdv, Htb, nump, denp);
    reduce_ln_k<<<NN, 128, 0, stream>>>(nump, denp, G1, LNW, LNB, HLN);

    // query projection
    gatin_k<128, 1><<<64, 256, 0, stream>>>(HLN, Wqb, BQ, nullptr, nullptr,
                                            nullptr, nullptr, Qb);

    // fused candidate head
    cand_k3<<<NN, 256, 0, stream>>>(CF, AM, Qb, Wc1b, Wc2b, Wfu,
                                    BC1, BC2, BS1, WS2, BS2, OUT);
}

// Round 5
// 389.199 us; speedup vs baseline: 2.6316x; 1.0832x over previous
//
#include <hip/hip_runtime.h>
#include <hip/hip_bf16.h>
#include <math.h>

#define NN 4096
#define HD 128
#define NCAND 64
#define NCF 10
#define NSEG 8
#define NEGV (-1000000000.0f)

typedef __attribute__((ext_vector_type(8))) short short8_t;
typedef __attribute__((ext_vector_type(4))) float f32x4_t;

// ---- bf16 helpers ---------------------------------------------------------
__device__ __forceinline__ short f2bf(float f) {
    union { float f; unsigned u; } v; v.f = f;
    unsigned r = (v.u + 0x7FFFu + ((v.u >> 16) & 1u)) >> 16;
    return (short)r;
}
__device__ __forceinline__ float bf2f(short s) {
    union { unsigned u; float f; } v; v.u = ((unsigned)(unsigned short)s) << 16;
    return v.f;
}
__device__ __forceinline__ unsigned pk2(float a, float b) {
    union { __hip_bfloat162 h; unsigned u; } v;
    v.h = __float22bfloat162_rn(make_float2(a, b));
    return v.u;
}

// fast gelu: logistic form  x*sigmoid(1.702x) = x - x/(1+exp2(2.4555x))
__device__ __forceinline__ float gelu_f(float x) {
    float e = __builtin_amdgcn_exp2f(2.455466f * x);
    float r = __builtin_amdgcn_rcpf(e + 1.0f);
    return x - x * r;
}

// ---------------------------------------------------------------------------
// pack adjacency into bitmask
// ---------------------------------------------------------------------------
__global__ __launch_bounds__(256) void pack_k(
    const int* __restrict__ adj, unsigned* __restrict__ adjb)
{
    long g = (long)blockIdx.x * 256 + threadIdx.x;   // 524288 words
    const int4* p = (const int4*)adj + g * 8;
    unsigned w = 0;
    #pragma unroll
    for (int e = 0; e < 8; ++e) {
        int4 v = p[e];
        w |= (unsigned)(v.x != 0) << (e*4 + 0);
        w |= (unsigned)(v.y != 0) << (e*4 + 1);
        w |= (unsigned)(v.z != 0) << (e*4 + 2);
        w |= (unsigned)(v.w != 0) << (e*4 + 3);
    }
    adjb[g] = w;
}

// ---------------------------------------------------------------------------
// weight prep: all bf16 conversions
// ---------------------------------------------------------------------------
__global__ __launch_bounds__(256) void wprep_k(
    const float* __restrict__ Wc1, const float* __restrict__ Wc2,
    const float* __restrict__ Ws1, const float* __restrict__ W1,
    const float* __restrict__ W2, const float* __restrict__ Wq,
    short* __restrict__ Wc1b, short* __restrict__ Wc2b, short* __restrict__ Wfu,
    short* __restrict__ W1b, short* __restrict__ W2b, short* __restrict__ Wqb)
{
    int g = blockIdx.x * 256 + threadIdx.x;
    int tot = gridDim.x * 256;
    for (int e = g; e < 128*32; e += tot) {
        int t = e >> 5, k = e & 31;
        Wc1b[e] = (k < NCF) ? f2bf(Wc1[t*NCF + k]) : (short)0;
    }
    for (int e = g; e < 128*128; e += tot) Wc2b[e] = f2bf(Wc2[e]);
    for (int e = g; e < 128*256; e += tot) {
        int h = e >> 8, j = e & 255;
        float v = (j < 128) ? Ws1[h*256 + 128 + j] : Ws1[h*256 + (j - 128)];
        Wfu[e] = f2bf(v);
    }
    for (int e = g; e < 128*64;  e += tot) W1b[e] = f2bf(W1[e]);
    for (int e = g; e < 128*128; e += tot) W2b[e] = f2bf(W2[e]);
    for (int e = g; e < 128*128; e += tot) Wqb[e] = f2bf(Wq[e]);
}

// ---------------------------------------------------------------------------
// input transform, M=16/block (grid 256): H = in @ W^T via bf16 MFMA.
// MODE 0: emit s/d scalars + transposed bf16 Htb. MODE 1: H+bias -> f32 out.
// A-frags built directly from global (no staging LDS).
// ---------------------------------------------------------------------------
template<int K, int MODE>
__global__ __launch_bounds__(256) void gatin_k2(
    const float* __restrict__ in, const short* __restrict__ Wb,
    const float* __restrict__ bias,
    const float* __restrict__ a_s, const float* __restrict__ a_d,
    float* __restrict__ sdv, short* __restrict__ Htb,
    float* __restrict__ outq)
{
    __shared__ float H_s[16*132];
    int tid = threadIdx.x;
    int n0 = blockIdx.x * 16;
    int w = tid >> 6, l = tid & 63, l15 = l & 15, qd = l >> 4;

    f32x4_t acc[2];
    acc[0] = (f32x4_t){0.f,0.f,0.f,0.f};
    acc[1] = (f32x4_t){0.f,0.f,0.f,0.f};
    const float* arow = in + (long)(n0 + l15) * K;
    #pragma unroll
    for (int kc = 0; kc < K/32; ++kc) {
        int k0 = kc*32 + qd*8;
        float4 x = *(const float4*)&arow[k0];
        float4 y = *(const float4*)&arow[k0+4];
        union { short8_t s; unsigned u[4]; } a;
        a.u[0]=pk2(x.x,x.y); a.u[1]=pk2(x.z,x.w);
        a.u[2]=pk2(y.x,y.y); a.u[3]=pk2(y.z,y.w);
        #pragma unroll
        for (int it = 0; it < 2; ++it) {
            short8_t b = *(const short8_t*)&Wb[((w*2+it)*16 + l15)*K + k0];
            acc[it] = __builtin_amdgcn_mfma_f32_16x16x32_bf16(a.s, b, acc[it], 0,0,0);
        }
    }
    if (MODE == 1) {
        #pragma unroll
        for (int it = 0; it < 2; ++it) {
            int n = (w*2+it)*16 + l15;
            float bv = bias[n];
            #pragma unroll
            for (int r = 0; r < 4; ++r)
                outq[(long)(n0 + qd*4 + r)*HD + n] = acc[it][r] + bv;
        }
        return;
    }
    #pragma unroll
    for (int it = 0; it < 2; ++it)
        #pragma unroll
        for (int r = 0; r < 4; ++r)
            H_s[(qd*4+r)*132 + (w*2+it)*16 + l15] = acc[it][r];
    __syncthreads();
    {   // s/d dot products
        int row = tid >> 4, sg = tid & 15;
        int h0 = sg*8;
        float4 as0 = *(const float4*)&a_s[h0];
        float4 as1 = *(const float4*)&a_s[h0+4];
        float4 ad0 = *(const float4*)&a_d[h0];
        float4 ad1 = *(const float4*)&a_d[h0+4];
        float hv[8];
        #pragma unroll
        for (int e = 0; e < 8; ++e) hv[e] = H_s[row*132 + h0 + e];
        float sp = hv[0]*as0.x + hv[1]*as0.y + hv[2]*as0.z + hv[3]*as0.w
                 + hv[4]*as1.x + hv[5]*as1.y + hv[6]*as1.z + hv[7]*as1.w;
        float dp = hv[0]*ad0.x + hv[1]*ad0.y + hv[2]*ad0.z + hv[3]*ad0.w
                 + hv[4]*ad1.x + hv[5]*ad1.y + hv[6]*ad1.z + hv[7]*ad1.w;
        sp += __shfl_xor(sp,1); sp += __shfl_xor(sp,2);
        sp += __shfl_xor(sp,4); sp += __shfl_xor(sp,8);
        dp += __shfl_xor(dp,1); dp += __shfl_xor(dp,2);
        dp += __shfl_xor(dp,4); dp += __shfl_xor(dp,8);
        if (sg == 0) { sdv[n0+row] = sp; sdv[NN + n0 + row] = dp; }
    }
    {   // transpose -> Htb bf16
        int h = tid & 127, pr = tid >> 7;
        unsigned u[4];
        #pragma unroll
        for (int c2 = 0; c2 < 4; ++c2)
            u[c2] = pk2(H_s[(pr*8 + 2*c2)*132 + h], H_s[(pr*8 + 2*c2 + 1)*132 + h]);
        *(uint4*)&Htb[(long)h*NN + n0 + pr*8] = make_uint4(u[0],u[1],u[2],u[3]);
    }
}

// ---------------------------------------------------------------------------
// GAT aggregate v3: ZERO barriers, ZERO LDS. Each lane builds its own MFMA
// A-frag entries (per-edge exp2), B direct from Htb. Grid (64 i-tiles, NSEG).
// ---------------------------------------------------------------------------
__global__ __launch_bounds__(256, 4) void agg_k3(
    const unsigned* __restrict__ adjb, const float* __restrict__ sdv,
    const short* __restrict__ Htb, float* __restrict__ num_part,
    float* __restrict__ den_part)
{
    int tid = threadIdx.x;
    int i0 = blockIdx.x * 64;
    int seg = blockIdx.y;
    int w = tid >> 6, l = tid & 63, l15 = l & 15, qd = l >> 4;
    int arow = i0 + w*16 + l15;               // i-row this lane builds A for
    float si = sdv[arow];
    const float* d_ = sdv + NN;
    const float C1 = 1.44269504f;             // log2(e)
    const float C2 = 0.28853901f;             // 0.2*log2(e)
    f32x4_t acc[8];
    #pragma unroll
    for (int nt = 0; nt < 8; ++nt) acc[nt] = (f32x4_t){0.f,0.f,0.f,0.f};
    float den = 0.f;

    #pragma unroll 2
    for (int c = 0; c < 16; ++c) {
        int j0 = seg*512 + c*32;
        int jb = j0 + qd*8;
        float4 da = *(const float4*)&d_[jb];
        float4 db = *(const float4*)&d_[jb+4];
        unsigned word = adjb[(long)arow*128 + (j0 >> 5)];
        unsigned byte_ = (word >> (qd*8)) & 0xffu;
        float dv[8] = {da.x,da.y,da.z,da.w,db.x,db.y,db.z,db.w};
        float v[8];
        #pragma unroll
        for (int e = 0; e < 8; ++e) {
            float z = si + dv[e];
            float k = (z > 0.f) ? C1 : C2;
            float wv = __builtin_amdgcn_exp2f(z * k);
            v[e] = ((byte_ >> e) & 1u) ? wv : 0.f;
            den += v[e];
        }
        union { short8_t s; unsigned u[4]; } a;
        a.u[0]=pk2(v[0],v[1]); a.u[1]=pk2(v[2],v[3]);
        a.u[2]=pk2(v[4],v[5]); a.u[3]=pk2(v[6],v[7]);
        #pragma unroll
        for (int nt = 0; nt < 8; ++nt) {
            short8_t b = *(const short8_t*)&Htb[(long)(nt*16 + l15)*NN + jb];
            acc[nt] = __builtin_amdgcn_mfma_f32_16x16x32_bf16(a.s, b, acc[nt], 0,0,0);
        }
    }
    den += __shfl_xor(den, 16); den += __shfl_xor(den, 32);
    if (qd == 0) den_part[seg*NN + arow] = den;
    long base = (long)seg*NN*HD;
    #pragma unroll
    for (int nt = 0; nt < 8; ++nt)
        #pragma unroll
        for (int r = 0; r < 4; ++r)
            num_part[base + (long)(i0 + w*16 + qd*4 + r)*HD + nt*16 + l15] = acc[nt][r];
}

// ---------------------------------------------------------------------------
__global__ __launch_bounds__(128) void reduce_relu_k(
    const float* __restrict__ num_part, const float* __restrict__ den_part,
    float* __restrict__ G)
{
    int row = blockIdx.x, t = threadIdx.x;
    float n = 0.f, d = 0.f;
    #pragma unroll
    for (int s = 0; s < NSEG; ++s) {
        n += num_part[(long)s*NN*HD + (long)row*HD + t];
        d += den_part[s*NN + row];
    }
    float v = (d > 0.f) ? n/d : 0.f;
    G[(long)row*HD + t] = fmaxf(v, 0.f);
}

__global__ __launch_bounds__(128) void reduce_ln_k(
    const float* __restrict__ num_part, const float* __restrict__ den_part,
    const float* __restrict__ G1, const float* __restrict__ ln_w,
    const float* __restrict__ ln_b, float* __restrict__ HLN)
{
    __shared__ float r1[2], r2[2];
    int row = blockIdx.x, t = threadIdx.x;
    float n = 0.f, d = 0.f;
    #pragma unroll
    for (int s = 0; s < NSEG; ++s) {
        n += num_part[(long)s*NN*HD + (long)row*HD + t];
        d += den_part[s*NN + row];
    }
    float v = (d > 0.f) ? n/d : 0.f;
    v = fmaxf(v, 0.f) + G1[(long)row*HD + t];
    float sum = v, sq = v*v;
    #pragma unroll
    for (int off = 32; off > 0; off >>= 1) {
        sum += __shfl_xor(sum, off);
        sq  += __shfl_xor(sq, off);
    }
    int wid = t >> 6;
    if ((t & 63) == 0) { r1[wid] = sum; r2[wid] = sq; }
    __syncthreads();
    float mu  = (r1[0]+r1[1]) * (1.0f/128.0f);
    float var = (r2[0]+r2[1]) * (1.0f/128.0f) - mu*mu;
    HLN[(long)row*HD + t] = (v - mu) * rsqrtf(var + 1e-5f) * ln_w[t] + ln_b[t];
}

// u-frag helpers
__device__ __forceinline__ short8_t mulq(short8_t c, const float* qp) {
    union { short8_t s; unsigned u[4]; } r;
    #pragma unroll
    for (int p = 0; p < 4; ++p) {
        float v0 = bf2f(c[2*p])   * qp[2*p];
        float v1 = bf2f(c[2*p+1]) * qp[2*p+1];
        r.u[p] = pk2(v0, v1);
    }
    return r.s;
}
__device__ __forceinline__ short8_t mulq2(short8_t c, float4 qa, float4 qb) {
    union { short8_t s; unsigned u[4]; } r;
    r.u[0] = pk2(bf2f(c[0])*qa.x, bf2f(c[1])*qa.y);
    r.u[1] = pk2(bf2f(c[2])*qa.z, bf2f(c[3])*qa.w);
    r.u[2] = pk2(bf2f(c[4])*qb.x, bf2f(c[5])*qb.y);
    r.u[3] = pk2(bf2f(c[6])*qb.z, bf2f(c[7])*qb.w);
    return r.s;
}

// ---------------------------------------------------------------------------
// cand stage A: cand2 = gelu(gelu(cf@Wc1^T+b1)@Wc2^T+b2), 2 nodes (M=128)
// per block, ONE barrier. Also precomputes per-row feature bias -> biasb.
// ---------------------------------------------------------------------------
__global__ __launch_bounds__(256, 3) void cand_a_k(
    const float* __restrict__ cf,
    const short* __restrict__ Wc1b, const short* __restrict__ Wc2b,
    const float* __restrict__ bc1, const float* __restrict__ bc2,
    float* __restrict__ biasb, short* __restrict__ cand2)
{
    __shared__ __align__(16) short cand_s[128*136];
    int tid = threadIdx.x;
    long r0 = (long)blockIdx.x * 128;
    int w = tid >> 6, l = tid & 63, l15 = l & 15, qd = l >> 4;

    // G1 A-frags direct from cf + bias precompute
    short8_t fa[2];
    #pragma unroll
    for (int im = 0; im < 2; ++im) {
        long row = r0 + (w*2+im)*16 + l15;
        union { short8_t s; unsigned u[4]; } a;
        float bp = 0.f;
        if (qd == 0) {
            float4 x = *(const float4*)&cf[row*10];
            float4 y = *(const float4*)&cf[row*10+4];
            a.u[0]=pk2(x.x,x.y); a.u[1]=pk2(x.z,x.w);
            a.u[2]=pk2(y.x,y.y); a.u[3]=pk2(y.z,y.w);
            bp = 20.0f*x.x + 1.5f*x.y - 1.5f*x.z + 4.0f*y.x
               + 1.5f*y.y + 1.2f*y.z + 2.5f*y.w;
        } else if (qd == 1) {
            float2 x = *(const float2*)&cf[row*10+8];
            a.u[0]=pk2(x.x,x.y); a.u[1]=0; a.u[2]=0; a.u[3]=0;
            bp = 1.6f*x.x + 1.2f*x.y;
        } else { a.u[0]=a.u[1]=a.u[2]=a.u[3]=0; }
        bp += __shfl_xor(bp, 16);
        if (qd == 0) biasb[row] = bp;
        fa[im] = a.s;
    }
    f32x4_t acc[2][8];
    #pragma unroll
    for (int im = 0; im < 2; ++im)
        #pragma unroll
        for (int nt = 0; nt < 8; ++nt) acc[im][nt] = (f32x4_t){0.f,0.f,0.f,0.f};
    #pragma unroll
    for (int nt = 0; nt < 8; ++nt) {
        short8_t b = *(const short8_t*)&Wc1b[(nt*16 + l15)*32 + qd*8];
        acc[0][nt] = __builtin_amdgcn_mfma_f32_16x16x32_bf16(fa[0], b, acc[0][nt], 0,0,0);
        acc[1][nt] = __builtin_amdgcn_mfma_f32_16x16x32_bf16(fa[1], b, acc[1][nt], 0,0,0);
    }
    #pragma unroll
    for (int im = 0; im < 2; ++im)
        #pragma unroll
        for (int nt = 0; nt < 8; ++nt) {
            int n = nt*16 + l15;
            float bv = bc1[n];
            #pragma unroll
            for (int r = 0; r < 4; ++r)
                cand_s[((w*2+im)*16 + qd*4 + r)*136 + n] =
                    f2bf(gelu_f(acc[im][nt][r] + bv));
        }
    __syncthreads();

    // G2
    #pragma unroll
    for (int im = 0; im < 2; ++im)
        #pragma unroll
        for (int nt = 0; nt < 8; ++nt) acc[im][nt] = (f32x4_t){0.f,0.f,0.f,0.f};
    #pragma unroll
    for (int kc = 0; kc < 4; ++kc) {
        int k0 = kc*32 + qd*8;
        short8_t a0 = *(const short8_t*)&cand_s[((w*2+0)*16 + l15)*136 + k0];
        short8_t a1 = *(const short8_t*)&cand_s[((w*2+1)*16 + l15)*136 + k0];
        #pragma unroll
        for (int nt = 0; nt < 8; ++nt) {
            short8_t b = *(const short8_t*)&Wc2b[(nt*16 + l15)*128 + k0];
            acc[0][nt] = __builtin_amdgcn_mfma_f32_16x16x32_bf16(a0, b, acc[0][nt], 0,0,0);
            acc[1][nt] = __builtin_amdgcn_mfma_f32_16x16x32_bf16(a1, b, acc[1][nt], 0,0,0);
        }
    }
    #pragma unroll
    for (int im = 0; im < 2; ++im)
        #pragma unroll
        for (int nt = 0; nt < 8; ++nt) {
            int n = nt*16 + l15;
            float bv = bc2[n];
            #pragma unroll
            for (int r = 0; r < 4; ++r) {
                long row = r0 + (w*2+im)*16 + qd*4 + r;
                cand2[row*128 + n] = f2bf(gelu_f(acc[im][nt][r] + bv));
            }
        }
}

// ---------------------------------------------------------------------------
// cand stage B: logits = gelu([cand2|q.cand2]@Wfu^T+bs1)@ws2 + bias, masked.
// 2 nodes (M=128) per block, ZERO barriers, ZERO LDS.
// ---------------------------------------------------------------------------
__global__ __launch_bounds__(256, 3) void cand_b_k(
    const short* __restrict__ cand2, const short* __restrict__ Wfu,
    const float* __restrict__ Qb, const float* __restrict__ biasb,
    const float* __restrict__ am, const float* __restrict__ bs1,
    const float* __restrict__ Ws2, const float* __restrict__ bs2,
    float* __restrict__ out)
{
    int tid = threadIdx.x;
    long r0 = (long)blockIdx.x * 128;
    int w = tid >> 6, l = tid & 63, l15 = l & 15, qd = l >> 4;
    int node = (int)(r0 >> 6) + (w >> 1);

    // no-valid flag per node (wave-wide reduce)
    float amv = am[(long)node*64 + l];
    float tot = amv;
    #pragma unroll
    for (int off = 32; off > 0; off >>= 1) tot += __shfl_xor(tot, off);
    bool noval = (tot <= 0.f);

    f32x4_t acc[2][8];
    #pragma unroll
    for (int im = 0; im < 2; ++im)
        #pragma unroll
        for (int nt = 0; nt < 8; ++nt) acc[im][nt] = (f32x4_t){0.f,0.f,0.f,0.f};
    const float* qrow = Qb + (long)node*HD;

    #pragma unroll
    for (int kc = 0; kc < 4; ++kc) {
        int k0 = kc*32 + qd*8;
        short8_t a0 = *(const short8_t*)&cand2[(r0 + (w*2+0)*16 + l15)*128 + k0];
        short8_t a1 = *(const short8_t*)&cand2[(r0 + (w*2+1)*16 + l15)*128 + k0];
        #pragma unroll
        for (int nt = 0; nt < 8; ++nt) {
            short8_t b = *(const short8_t*)&Wfu[(nt*16 + l15)*256 + k0];
            acc[0][nt] = __builtin_amdgcn_mfma_f32_16x16x32_bf16(a0, b, acc[0][nt], 0,0,0);
            acc[1][nt] = __builtin_amdgcn_mfma_f32_16x16x32_bf16(a1, b, acc[1][nt], 0,0,0);
        }
        float4 qa = *(const float4*)&qrow[k0];
        float4 qb = *(const float4*)&qrow[k0+4];
        short8_t aq0 = mulq2(a0, qa, qb);
        short8_t aq1 = mulq2(a1, qa, qb);
        #pragma unroll
        for (int nt = 0; nt < 8; ++nt) {
            short8_t b = *(const short8_t*)&Wfu[(nt*16 + l15)*256 + 128 + k0];
            acc[0][nt] = __builtin_amdgcn_mfma_f32_16x16x32_bf16(aq0, b, acc[0][nt], 0,0,0);
            acc[1][nt] = __builtin_amdgcn_mfma_f32_16x16x32_bf16(aq1, b, acc[1][nt], 0,0,0);
        }
    }

    // epilogue
    float bs1v[8], ws2v[8];
    #pragma unroll
    for (int nt = 0; nt < 8; ++nt) {
        int n = nt*16 + l15;
        bs1v[nt] = bs1[n];
        ws2v[nt] = Ws2[n];
    }
    float b2v = bs2[0];
    #pragma unroll
    for (int im = 0; im < 2; ++im)
        #pragma unroll
        for (int r = 0; r < 4; ++r) {
            float p = 0.f;
            #pragma unroll
            for (int nt = 0; nt < 8; ++nt)
                p += gelu_f(acc[im][nt][r] + bs1v[nt]) * ws2v[nt];
            p += __shfl_xor(p,1); p += __shfl_xor(p,2);
            p += __shfl_xor(p,4); p += __shfl_xor(p,8);
            if (l15 == 0) {
                long row = r0 + (w*2+im)*16 + qd*4 + r;
                float lg = p + b2v + biasb[row];
                float m = am[row];
                if (((int)(row & 63)) == 0 && noval) m = 1.0f;
                out[row] = (m > 0.f) ? lg : NEGV;
            }
        }
}

// ---------------------------------------------------------------------------
// fallback fused candidate head (round-4), used if ws too small for cand2
// ---------------------------------------------------------------------------
__global__ __launch_bounds__(256, 5) void cand_k3(
    const float* __restrict__ cf, const float* __restrict__ am,
    const float* __restrict__ Qb,
    const short* __restrict__ Wc1b, const short* __restrict__ Wc2b,
    const short* __restrict__ Wfu,
    const float* __restrict__ bc1, const float* __restrict__ bc2,
    const float* __restrict__ bs1, const float* __restrict__ Ws2,
    const float* __restrict__ bs2, float* __restrict__ out)
{
    __shared__ __align__(16) short cand_s[64*136];
    __shared__ float b1_s[128], b2_s[128], bs1_s[128], ws2_s[128], q_s[128];
    __shared__ float red_s[64*2];

    int tid = threadIdx.x;
    int node = blockIdx.x;
    const float* cfn = cf + (long)node*NCAND*NCF;

    if (tid < 128) {
        b1_s[tid]  = bc1[tid];
        b2_s[tid]  = bc2[tid];
        bs1_s[tid] = bs1[tid];
        ws2_s[tid] = Ws2[tid];
        q_s[tid]   = Qb[(long)node*HD + tid];
    }
    int w = tid >> 6, l = tid & 63, l15 = l & 15, qd = l >> 4;
    int mt0 = (w >> 1) * 2, nt0 = (w & 1) * 4;

    short8_t fa[2];
    #pragma unroll
    for (int im = 0; im < 2; ++im) {
        int c = (mt0+im)*16 + l15;
        union { short8_t s; unsigned u[4]; } r;
        if (qd == 0) {
            float4 x = *(const float4*)&cfn[c*10];
            float4 y = *(const float4*)&cfn[c*10 + 4];
            r.u[0] = pk2(x.x, x.y); r.u[1] = pk2(x.z, x.w);
            r.u[2] = pk2(y.x, y.y); r.u[3] = pk2(y.z, y.w);
        } else if (qd == 1) {
            float2 x = *(const float2*)&cfn[c*10 + 8];
            r.u[0] = pk2(x.x, x.y); r.u[1] = 0; r.u[2] = 0; r.u[3] = 0;
        } else { r.u[0] = r.u[1] = r.u[2] = r.u[3] = 0; }
        fa[im] = r.s;
    }
    __syncthreads();

    f32x4_t acc[2][4];
    #pragma unroll
    for (int im = 0; im < 2; ++im)
        #pragma unroll
        for (int in_ = 0; in_ < 4; ++in_) acc[im][in_] = (f32x4_t){0.f,0.f,0.f,0.f};
    #pragma unroll
    for (int in_ = 0; in_ < 4; ++in_) {
        short8_t b = *(const short8_t*)&Wc1b[((nt0+in_)*16 + l15)*32 + qd*8];
        acc[0][in_] = __builtin_amdgcn_mfma_f32_16x16x32_bf16(fa[0], b, acc[0][in_], 0,0,0);
        acc[1][in_] = __builtin_amdgcn_mfma_f32_16x16x32_bf16(fa[1], b, acc[1][in_], 0,0,0);
    }
    #pragma unroll
    for (int im = 0; im < 2; ++im)
        #pragma unroll
        for (int in_ = 0; in_ < 4; ++in_)
            #pragma unroll
            for (int r = 0; r < 4; ++r) {
                int c = (mt0+im)*16 + qd*4 + r;
                int n = (nt0+in_)*16 + l15;
                cand_s[c*136 + n] = f2bf(gelu_f(acc[im][in_][r] + b1_s[n]));
            }
    __syncthreads();

    #pragma unroll
    for (int im = 0; im < 2; ++im)
        #pragma unroll
        for (int in_ = 0; in_ < 4; ++in_) acc[im][in_] = (f32x4_t){0.f,0.f,0.f,0.f};
    #pragma unroll
    for (int kc = 0; kc < 4; ++kc) {
        int k0 = kc*32 + qd*8;
        short8_t a0 = *(const short8_t*)&cand_s[(mt0*16 + l15)*136 + k0];
        short8_t a1 = *(const short8_t*)&cand_s[((mt0+1)*16 + l15)*136 + k0];
        #pragma unroll
        for (int in_ = 0; in_ < 4; ++in_) {
            short8_t b = *(const short8_t*)&Wc2b[((nt0+in_)*16 + l15)*128 + k0];
            acc[0][in_] = __builtin_amdgcn_mfma_f32_16x16x32_bf16(a0, b, acc[0][in_], 0,0,0);
            acc[1][in_] = __builtin_amdgcn_mfma_f32_16x16x32_bf16(a1, b, acc[1][in_], 0,0,0);
        }
    }
    __syncthreads();
    #pragma unroll
    for (int im = 0; im < 2; ++im)
        #pragma unroll
        for (int in_ = 0; in_ < 4; ++in_)
            #pragma unroll
            for (int r = 0; r < 4; ++r) {
                int c = (mt0+im)*16 + qd*4 + r;
                int n = (nt0+in_)*16 + l15;
                cand_s[c*136 + n] = f2bf(gelu_f(acc[im][in_][r] + b2_s[n]));
            }
    __syncthreads();

    #pragma unroll
    for (int im = 0; im < 2; ++im)
        #pragma unroll
        for (int in_ = 0; in_ < 4; ++in_) acc[im][in_] = (f32x4_t){0.f,0.f,0.f,0.f};
    #pragma unroll
    for (int kc = 0; kc < 4; ++kc) {
        int k0 = kc*32 + qd*8;
        short8_t a0 = *(const short8_t*)&cand_s[(mt0*16 + l15)*136 + k0];
        short8_t a1 = *(const short8_t*)&cand_s[((mt0+1)*16 + l15)*136 + k0];
        #pragma unroll
        for (int in_ = 0; in_ < 4; ++in_) {
            short8_t b = *(const short8_t*)&Wfu[((nt0+in_)*16 + l15)*256 + k0];
            acc[0][in_] = __builtin_amdgcn_mfma_f32_16x16x32_bf16(a0, b, acc[0][in_], 0,0,0);
            acc[1][in_] = __builtin_amdgcn_mfma_f32_16x16x32_bf16(a1, b, acc[1][in_], 0,0,0);
        }
        short8_t aq0 = mulq(a0, &q_s[k0]);
        short8_t aq1 = mulq(a1, &q_s[k0]);
        #pragma unroll
        for (int in_ = 0; in_ < 4; ++in_) {
            short8_t b = *(const short8_t*)&Wfu[((nt0+in_)*16 + l15)*256 + 128 + k0];
            acc[0][in_] = __builtin_amdgcn_mfma_f32_16x16x32_bf16(aq0, b, acc[0][in_], 0,0,0);
            acc[1][in_] = __builtin_amdgcn_mfma_f32_16x16x32_bf16(aq1, b, acc[1][in_], 0,0,0);
        }
    }
    #pragma unroll
    for (int im = 0; im < 2; ++im)
        #pragma unroll
        for (int r = 0; r < 4; ++r) {
            float p = 0.f;
            #pragma unroll
            for (int in_ = 0; in_ < 4; ++in_) {
                int n = (nt0+in_)*16 + l15;
                p += gelu_f(acc[im][in_][r] + bs1_s[n]) * ws2_s[n];
            }
            p += __shfl_xor(p, 1); p += __shfl_xor(p, 2);
            p += __shfl_xor(p, 4); p += __shfl_xor(p, 8);
            if (l15 == 0)
                red_s[((mt0+im)*16 + qd*4 + r)*2 + (w&1)] = p;
        }
    __syncthreads();

    if (tid < 64) {
        int c = tid;
        float lg = red_s[c*2] + red_s[c*2+1] + bs2[0];
        const float* r = cfn + c*10;
        lg += 20.0f*r[0] + 4.0f*r[4] + 1.5f*r[5] + 1.5f*r[1] - 1.5f*r[2]
            + 1.2f*r[6] + 2.5f*r[7] + 1.6f*r[8] + 1.2f*r[9];
        float m = am[(long)node*NCAND + c];
        float tot = m;
        #pragma unroll
        for (int off = 32; off > 0; off >>= 1) tot += __shfl_xor(tot, off);
        if (c == 0 && tot <= 0.f) m = 1.0f;
        out[(long)node*NCAND + c] = (m > 0.f) ? lg : NEGV;
    }
}

// ---------------------------------------------------------------------------
extern "C" void kernel_launch(void* const* d_in, const int* in_sizes, int n_in,
                              void* d_out, int out_size, void* d_ws, size_t ws_size,
                              hipStream_t stream)
{
    const float* X   = (const float*)d_in[0];
    const float* CF  = (const float*)d_in[1];
    const int*   ADJ = (const int*)d_in[2];
    const float* AM  = (const float*)d_in[3];
    const float* W1  = (const float*)d_in[4];
    const float* A1S = (const float*)d_in[5];
    const float* A1D = (const float*)d_in[6];
    const float* W2  = (const float*)d_in[7];
    const float* A2S = (const float*)d_in[8];
    const float* A2D = (const float*)d_in[9];
    const float* LNW = (const float*)d_in[10];
    const float* LNB = (const float*)d_in[11];
    const float* WC1 = (const float*)d_in[12];
    const float* BC1 = (const float*)d_in[13];
    const float* WC2 = (const float*)d_in[14];
    const float* BC2 = (const float*)d_in[15];
    const float* WQ  = (const float*)d_in[16];
    const float* BQ  = (const float*)d_in[17];
    const float* WS1 = (const float*)d_in[18];
    const float* BS1 = (const float*)d_in[19];
    const float* WS2 = (const float*)d_in[20];
    const float* BS2 = (const float*)d_in[21];
    float* OUT = (float*)d_out;

    float* ws = (float*)d_ws;
    float*    G1    = ws;                               // 524288
    float*    HLN   = ws + 524288;                      // 524288
    float*    Qb    = ws + 1048576;                     // 524288
    float*    sdv   = ws + 1572864;                     // 8192 (s,d)
    float*    denp  = ws + 1581056;                     // 32768
    short*    Htb   = (short*)(ws + 1613824);           // 524288 shorts
    unsigned* adjb  = (unsigned*)(ws + 1875968);        // 524288 words
    short*    Wc1b  = (short*)(ws + 2400256);           // 4096 shorts
    short*    Wc2b  = (short*)(ws + 2402304);           // 16384 shorts
    short*    Wfu   = (short*)(ws + 2410496);           // 32768 shorts
    short*    W1b   = (short*)(ws + 2426880);           // 8192 shorts
    short*    W2b   = (short*)(ws + 2430976);           // 16384 shorts
    short*    Wqb   = (short*)(ws + 2439168);           // 16384 shorts
    float*    biasb = ws + 2447360;                     // 262144
    float*    nump  = ws + 2709504;                     // 4194304
    short*    cand2 = (short*)(ws + 6903808);           // 33554432 shorts

    bool big_ws = (ws_size >= (size_t)23681024 * 4);

    // one-time preps
    wprep_k<<<64, 256, 0, stream>>>(WC1, WC2, WS1, W1, W2, WQ,
                                    Wc1b, Wc2b, Wfu, W1b, W2b, Wqb);
    pack_k<<<2048, 256, 0, stream>>>(ADJ, adjb);

    // GAT layer 1
    gatin_k2<64, 0><<<256, 256, 0, stream>>>(X, W1b, nullptr, A1S, A1D, sdv, Htb, nullptr);
    agg_k3<<<dim3(64, NSEG), 256, 0, stream>>>(adjb, sdv, Htb, nump, denp);
    reduce_relu_k<<<NN, 128, 0, stream>>>(nump, denp, G1);

    // GAT layer 2 + residual + LN
    gatin_k2<128, 0><<<256, 256, 0, stream>>>(G1, W2b, nullptr, A2S, A2D, sdv, Htb, nullptr);
    agg_k3<<<dim3(64, NSEG), 256, 0, stream>>>(adjb, sdv, Htb, nump, denp);
    reduce_ln_k<<<NN, 128, 0, stream>>>(nump, denp, G1, LNW, LNB, HLN);

    // query projection
    gatin_k2<128, 1><<<256, 256, 0, stream>>>(HLN, Wqb, BQ, nullptr, nullptr,
                                              nullptr, nullptr, Qb);

    if (big_ws) {
        cand_a_k<<<2048, 256, 0, stream>>>(CF, Wc1b, Wc2b, BC1, BC2, biasb, cand2);
        cand_b_k<<<2048, 256, 0, stream>>>(cand2, Wfu, Qb, biasb, AM,
                                           BS1, WS2, BS2, OUT);
    } else {
        cand_k3<<<NN, 256, 0, stream>>>(CF, AM, Qb, Wc1b, Wc2b, Wfu,
                                        BC1, BC2, BS1, WS2, BS2, OUT);
    }
}

// Round 7
// 369.087 us; speedup vs baseline: 2.7751x; 1.0545x over previous
//
#include <hip/hip_runtime.h>
#include <hip/hip_bf16.h>
#include <math.h>

#define NN 4096
#define HD 128
#define NCAND 64
#define NCF 10
#define NSEG 8
#define NEGV (-1000000000.0f)

typedef __attribute__((ext_vector_type(8))) short short8_t;
typedef __attribute__((ext_vector_type(4))) float f32x4_t;

// ---- bf16 helpers ---------------------------------------------------------
__device__ __forceinline__ short f2bf(float f) {
    union { float f; unsigned u; } v; v.f = f;
    unsigned r = (v.u + 0x7FFFu + ((v.u >> 16) & 1u)) >> 16;
    return (short)r;
}
__device__ __forceinline__ float bf2f(short s) {
    union { unsigned u; float f; } v; v.u = ((unsigned)(unsigned short)s) << 16;
    return v.f;
}
__device__ __forceinline__ unsigned pk2(float a, float b) {
    union { __hip_bfloat162 h; unsigned u; } v;
    v.h = __float22bfloat162_rn(make_float2(a, b));
    return v.u;
}

// fast gelu: logistic form  x*sigmoid(1.702x)
__device__ __forceinline__ float gelu_f(float x) {
    float e = __builtin_amdgcn_exp2f(2.455466f * x);
    float r = __builtin_amdgcn_rcpf(e + 1.0f);
    return x - x * r;
}

// ---------------------------------------------------------------------------
// prep: adjacency bitmask pack (blocks 0..2047) + candidate-weight bf16
// conversions (blocks 2048..2055)
// ---------------------------------------------------------------------------
__global__ __launch_bounds__(256) void prep_k(
    const int* __restrict__ adj, const float* __restrict__ Wc1,
    const float* __restrict__ Wc2, const float* __restrict__ Ws1,
    unsigned* __restrict__ adjb, short* __restrict__ Wc1b,
    short* __restrict__ Wc2b, short* __restrict__ Wfu)
{
    int tid = threadIdx.x;
    if (blockIdx.x < 2048) {
        long g = (long)blockIdx.x * 256 + tid;     // 524288 words
        const int4* p = (const int4*)adj + g * 8;
        unsigned w = 0;
        #pragma unroll
        for (int e = 0; e < 8; ++e) {
            int4 v = p[e];
            w |= (unsigned)(v.x != 0) << (e*4 + 0);
            w |= (unsigned)(v.y != 0) << (e*4 + 1);
            w |= (unsigned)(v.z != 0) << (e*4 + 2);
            w |= (unsigned)(v.w != 0) << (e*4 + 3);
        }
        adjb[g] = w;
    } else {
        int g = (blockIdx.x - 2048) * 256 + tid;
        const int tot = 8 * 256;
        for (int e = g; e < 128*32; e += tot) {
            int t = e >> 5, k = e & 31;
            Wc1b[e] = (k < NCF) ? f2bf(Wc1[t*NCF + k]) : (short)0;
        }
        for (int e = g; e < 128*128; e += tot) Wc2b[e] = f2bf(Wc2[e]);
        for (int e = g; e < 128*256; e += tot) {
            int h = e >> 8, j = e & 255;
            float v = (j < 128) ? Ws1[h*256 + 128 + j] : Ws1[h*256 + (j - 128)];
            Wfu[e] = f2bf(v);
        }
    }
}

// ---------------------------------------------------------------------------
// gatin: 16 rows/block, grid 256.
// IN 0: rows from global f32 `in` (X).
// IN 1: rows = relu(sum nump / sum den); also writes G1 (residual).
// IN 2: rows = LayerNorm(relu(sum/den) + G1).
// Then H = rows @ Wf^T (bf16 MFMA, Wf converted on the fly).
// OUT 0: s/d attention scalars + transposed bf16 Htb.
// OUT 1: H + bias -> f32 outq.
// ---------------------------------------------------------------------------
template<int K, int IN, int OUT>
__global__ __launch_bounds__(256) void gatin_k3(
    const float* __restrict__ in, const float* __restrict__ Wf,
    const float* __restrict__ nump, const float* __restrict__ denp,
    float* __restrict__ G1, const float* __restrict__ ln_w,
    const float* __restrict__ ln_b,
    const float* __restrict__ a_s, const float* __restrict__ a_d,
    float* __restrict__ sdv, short* __restrict__ Htb,
    const float* __restrict__ bias, float* __restrict__ outq)
{
    constexpr int AS = K + 4;
    __shared__ float in_s[16*AS];
    __shared__ float H_s[16*132];
    int tid = threadIdx.x;
    int n0 = blockIdx.x * 16;

    if (IN == 0) {
        // stage rows from global
        constexpr int NV = 16*K/4;    // float4 count
        for (int idx = tid; idx < NV; idx += 256) {
            int row = idx / (K/4), c4 = idx - row*(K/4);
            *(float4*)&in_s[row*AS + c4*4] = *(const float4*)&in[(long)(n0+row)*K + c4*4];
        }
    } else {
        int row = tid >> 4, c8 = (tid & 15) * 8;
        float v[8];
        #pragma unroll
        for (int i = 0; i < 8; ++i) v[i] = 0.f;
        float den = 0.f;
        #pragma unroll
        for (int s = 0; s < NSEG; ++s) {
            const float* np = nump + ((long)s*NN + n0 + row)*HD + c8;
            float4 a0 = *(const float4*)np;
            float4 a1 = *(const float4*)(np + 4);
            v[0]+=a0.x; v[1]+=a0.y; v[2]+=a0.z; v[3]+=a0.w;
            v[4]+=a1.x; v[5]+=a1.y; v[6]+=a1.z; v[7]+=a1.w;
            den += denp[s*NN + n0 + row];
        }
        float rd = (den > 0.f) ? __builtin_amdgcn_rcpf(den) : 0.f;
        if (den > 0.f) rd = rd * (2.0f - den * rd);   // NR refine
        #pragma unroll
        for (int i = 0; i < 8; ++i) v[i] = fmaxf(v[i]*rd, 0.f);
        if (IN == 1) {
            float4 o0 = make_float4(v[0],v[1],v[2],v[3]);
            float4 o1 = make_float4(v[4],v[5],v[6],v[7]);
            *(float4*)&G1[(long)(n0+row)*HD + c8]     = o0;
            *(float4*)&G1[(long)(n0+row)*HD + c8 + 4] = o1;
        } else {
            const float* gp = G1 + (long)(n0+row)*HD + c8;
            float4 g0 = *(const float4*)gp;
            float4 g1 = *(const float4*)(gp + 4);
            v[0]+=g0.x; v[1]+=g0.y; v[2]+=g0.z; v[3]+=g0.w;
            v[4]+=g1.x; v[5]+=g1.y; v[6]+=g1.z; v[7]+=g1.w;
            float sm = 0.f, sq = 0.f;
            #pragma unroll
            for (int i = 0; i < 8; ++i) { sm += v[i]; sq += v[i]*v[i]; }
            sm += __shfl_xor(sm,1); sq += __shfl_xor(sq,1);
            sm += __shfl_xor(sm,2); sq += __shfl_xor(sq,2);
            sm += __shfl_xor(sm,4); sq += __shfl_xor(sq,4);
            sm += __shfl_xor(sm,8); sq += __shfl_xor(sq,8);
            float mu  = sm * (1.0f/128.0f);
            float var = sq * (1.0f/128.0f) - mu*mu;
            float nr  = rsqrtf(var + 1e-5f);
            float4 lw0 = *(const float4*)&ln_w[c8];
            float4 lw1 = *(const float4*)&ln_w[c8+4];
            float4 lb0 = *(const float4*)&ln_b[c8];
            float4 lb1 = *(const float4*)&ln_b[c8+4];
            v[0]=(v[0]-mu)*nr*lw0.x+lb0.x; v[1]=(v[1]-mu)*nr*lw0.y+lb0.y;
            v[2]=(v[2]-mu)*nr*lw0.z+lb0.z; v[3]=(v[3]-mu)*nr*lw0.w+lb0.w;
            v[4]=(v[4]-mu)*nr*lw1.x+lb1.x; v[5]=(v[5]-mu)*nr*lw1.y+lb1.y;
            v[6]=(v[6]-mu)*nr*lw1.z+lb1.z; v[7]=(v[7]-mu)*nr*lw1.w+lb1.w;
        }
        #pragma unroll
        for (int i = 0; i < 8; ++i) in_s[row*AS + c8 + i] = v[i];
    }
    __syncthreads();

    int w = tid >> 6, l = tid & 63, l15 = l & 15, qd = l >> 4;
    f32x4_t acc[2];
    acc[0] = (f32x4_t){0.f,0.f,0.f,0.f};
    acc[1] = (f32x4_t){0.f,0.f,0.f,0.f};
    #pragma unroll
    for (int kc = 0; kc < K/32; ++kc) {
        int k0 = kc*32 + qd*8;
        float4 x = *(const float4*)&in_s[l15*AS + k0];
        float4 y = *(const float4*)&in_s[l15*AS + k0 + 4];
        union { short8_t s; unsigned u[4]; } a;
        a.u[0]=pk2(x.x,x.y); a.u[1]=pk2(x.z,x.w);
        a.u[2]=pk2(y.x,y.y); a.u[3]=pk2(y.z,y.w);
        #pragma unroll
        for (int it = 0; it < 2; ++it) {
            int n = (w*2+it)*16 + l15;
            float4 w0 = *(const float4*)&Wf[(long)n*K + k0];
            float4 w1 = *(const float4*)&Wf[(long)n*K + k0 + 4];
            union { short8_t s; unsigned u[4]; } b;
            b.u[0]=pk2(w0.x,w0.y); b.u[1]=pk2(w0.z,w0.w);
            b.u[2]=pk2(w1.x,w1.y); b.u[3]=pk2(w1.z,w1.w);
            acc[it] = __builtin_amdgcn_mfma_f32_16x16x32_bf16(a.s, b.s, acc[it], 0,0,0);
        }
    }

    if (OUT == 1) {
        #pragma unroll
        for (int it = 0; it < 2; ++it) {
            int n = (w*2+it)*16 + l15;
            float bv = bias[n];
            #pragma unroll
            for (int r = 0; r < 4; ++r)
                outq[(long)(n0 + qd*4 + r)*HD + n] = acc[it][r] + bv;
        }
        return;
    }

    #pragma unroll
    for (int it = 0; it < 2; ++it)
        #pragma unroll
        for (int r = 0; r < 4; ++r)
            H_s[(qd*4+r)*132 + (w*2+it)*16 + l15] = acc[it][r];
    __syncthreads();
    {   // s/d dot products
        int row = tid >> 4, sg = tid & 15;
        int h0 = sg*8;
        float4 as0 = *(const float4*)&a_s[h0];
        float4 as1 = *(const float4*)&a_s[h0+4];
        float4 ad0 = *(const float4*)&a_d[h0];
        float4 ad1 = *(const float4*)&a_d[h0+4];
        float hv[8];
        #pragma unroll
        for (int e = 0; e < 8; ++e) hv[e] = H_s[row*132 + h0 + e];
        float sp = hv[0]*as0.x + hv[1]*as0.y + hv[2]*as0.z + hv[3]*as0.w
                 + hv[4]*as1.x + hv[5]*as1.y + hv[6]*as1.z + hv[7]*as1.w;
        float dp = hv[0]*ad0.x + hv[1]*ad0.y + hv[2]*ad0.z + hv[3]*ad0.w
                 + hv[4]*ad1.x + hv[5]*ad1.y + hv[6]*ad1.z + hv[7]*ad1.w;
        sp += __shfl_xor(sp,1); sp += __shfl_xor(sp,2);
        sp += __shfl_xor(sp,4); sp += __shfl_xor(sp,8);
        dp += __shfl_xor(dp,1); dp += __shfl_xor(dp,2);
        dp += __shfl_xor(dp,4); dp += __shfl_xor(dp,8);
        if (sg == 0) { sdv[n0+row] = sp; sdv[NN + n0 + row] = dp; }
    }
    {   // transpose -> Htb bf16
        int h = tid & 127, pr = tid >> 7;
        unsigned u[4];
        #pragma unroll
        for (int c2 = 0; c2 < 4; ++c2)
            u[c2] = pk2(H_s[(pr*8 + 2*c2)*132 + h], H_s[(pr*8 + 2*c2 + 1)*132 + h]);
        *(uint4*)&Htb[(long)h*NN + n0 + pr*8] = make_uint4(u[0],u[1],u[2],u[3]);
    }
}

// ---------------------------------------------------------------------------
// GAT aggregate v4: zero barriers, zero LDS, M=32 i-rows/block, grid (128,8)
// -> 4 blocks/CU. Adjacency words prefetched to registers.
// ---------------------------------------------------------------------------
__global__ __launch_bounds__(256, 4) void agg_k4(
    const unsigned* __restrict__ adjb, const float* __restrict__ sdv,
    const short* __restrict__ Htb, float* __restrict__ num_part,
    float* __restrict__ den_part)
{
    int tid = threadIdx.x;
    int i0 = blockIdx.x * 32;
    int seg = blockIdx.y;
    int w = tid >> 6, l = tid & 63, l15 = l & 15, qd = l >> 4;
    int mh = w >> 1, nh = w & 1;
    int arow = i0 + mh*16 + l15;
    float si = sdv[arow];
    const float* d_ = sdv + NN;
    const float C1 = 1.44269504f;   // log2(e)
    const float C2 = 0.28853901f;   // 0.2*log2(e)

    unsigned wbuf[16];
    {
        const uint4* ap = (const uint4*)&adjb[(long)arow*128 + seg*16];
        uint4 q0 = ap[0], q1 = ap[1], q2 = ap[2], q3 = ap[3];
        wbuf[0]=q0.x; wbuf[1]=q0.y; wbuf[2]=q0.z; wbuf[3]=q0.w;
        wbuf[4]=q1.x; wbuf[5]=q1.y; wbuf[6]=q1.z; wbuf[7]=q1.w;
        wbuf[8]=q2.x; wbuf[9]=q2.y; wbuf[10]=q2.z; wbuf[11]=q2.w;
        wbuf[12]=q3.x; wbuf[13]=q3.y; wbuf[14]=q3.z; wbuf[15]=q3.w;
    }

    f32x4_t acc[4];
    #pragma unroll
    for (int nt = 0; nt < 4; ++nt) acc[nt] = (f32x4_t){0.f,0.f,0.f,0.f};
    float den = 0.f;

    #pragma unroll 4
    for (int c = 0; c < 16; ++c) {
        int j0 = seg*512 + c*32;
        int jb = j0 + qd*8;
        float4 da = *(const float4*)&d_[jb];
        float4 db = *(const float4*)&d_[jb+4];
        unsigned byte_ = (wbuf[c] >> (qd*8)) & 0xffu;
        float dv[8] = {da.x,da.y,da.z,da.w,db.x,db.y,db.z,db.w};
        float v[8];
        #pragma unroll
        for (int e = 0; e < 8; ++e) {
            float z = si + dv[e];
            float k = (z > 0.f) ? C1 : C2;
            float wv = __builtin_amdgcn_exp2f(z * k);
            v[e] = ((byte_ >> e) & 1u) ? wv : 0.f;
            den += v[e];
        }
        union { short8_t s; unsigned u[4]; } a;
        a.u[0]=pk2(v[0],v[1]); a.u[1]=pk2(v[2],v[3]);
        a.u[2]=pk2(v[4],v[5]); a.u[3]=pk2(v[6],v[7]);
        #pragma unroll
        for (int nt = 0; nt < 4; ++nt) {
            short8_t b = *(const short8_t*)&Htb[(long)(nh*64 + nt*16 + l15)*NN + jb];
            acc[nt] = __builtin_amdgcn_mfma_f32_16x16x32_bf16(a.s, b, acc[nt], 0,0,0);
        }
    }
    den += __shfl_xor(den, 16); den += __shfl_xor(den, 32);
    if (qd == 0 && nh == 0) den_part[seg*NN + arow] = den;
    long base = (long)seg*NN*HD;
    #pragma unroll
    for (int nt = 0; nt < 4; ++nt)
        #pragma unroll
        for (int r = 0; r < 4; ++r)
            num_part[base + (long)(i0 + mh*16 + qd*4 + r)*HD + nh*64 + nt*16 + l15]
                = acc[nt][r];
}

// u-frag helper
__device__ __forceinline__ short8_t mulq2(short8_t c, float4 qa, float4 qb) {
    union { short8_t s; unsigned u[4]; } r;
    r.u[0] = pk2(bf2f(c[0])*qa.x, bf2f(c[1])*qa.y);
    r.u[1] = pk2(bf2f(c[2])*qa.z, bf2f(c[3])*qa.w);
    r.u[2] = pk2(bf2f(c[4])*qb.x, bf2f(c[5])*qb.y);
    r.u[3] = pk2(bf2f(c[6])*qb.z, bf2f(c[7])*qb.w);
    return r.s;
}

// ---------------------------------------------------------------------------
// fused candidate head v4b: 2 nodes (M=128) per block, each wave owns 32 rows
// end-to-end. LDS phase boundaries protected by __syncthreads() — the
// round-6 barrier-free variant diverged after warm-up (wave-private-LDS
// ordering assumption unsafe in practice).
// ---------------------------------------------------------------------------
__global__ __launch_bounds__(256, 3) void cand_k4(
    const float* __restrict__ cf, const float* __restrict__ am,
    const float* __restrict__ Qb,
    const short* __restrict__ Wc1b, const short* __restrict__ Wc2b,
    const short* __restrict__ Wfu,
    const float* __restrict__ bc1, const float* __restrict__ bc2,
    const float* __restrict__ bs1, const float* __restrict__ Ws2,
    const float* __restrict__ bs2, float* __restrict__ out)
{
    __shared__ __align__(16) short cand_s[128*136];
    __shared__ float bias_s[128];
    int tid = threadIdx.x;
    long r0 = (long)blockIdx.x * 128;
    int w = tid >> 6, l = tid & 63, l15 = l & 15, qd = l >> 4;
    int node = (int)(r0 >> 6) + (w >> 1);

    // per-node "no valid action" flag (wave-wide over 64 candidates)
    float amv = am[r0 + (long)(w >> 1)*64 + l];
    float tot = amv;
    #pragma unroll
    for (int off = 32; off > 0; off >>= 1) tot += __shfl_xor(tot, off);
    bool noval = (tot <= 0.f);

    // ---- GEMM1: A-frags direct from cf; feature-bias into bias_s ----------
    short8_t fa[2];
    #pragma unroll
    for (int im = 0; im < 2; ++im) {
        long row = r0 + (w*2+im)*16 + l15;
        union { short8_t s; unsigned u[4]; } a;
        float bp = 0.f;
        if (qd == 0) {
            float4 x = *(const float4*)&cf[row*10];
            float4 y = *(const float4*)&cf[row*10+4];
            a.u[0]=pk2(x.x,x.y); a.u[1]=pk2(x.z,x.w);
            a.u[2]=pk2(y.x,y.y); a.u[3]=pk2(y.z,y.w);
            bp = 20.0f*x.x + 1.5f*x.y - 1.5f*x.z + 4.0f*y.x
               + 1.5f*y.y + 1.2f*y.z + 2.5f*y.w;
        } else if (qd == 1) {
            float2 x = *(const float2*)&cf[row*10+8];
            a.u[0]=pk2(x.x,x.y); a.u[1]=0; a.u[2]=0; a.u[3]=0;
            bp = 1.6f*x.x + 1.2f*x.y;
        } else { a.u[0]=a.u[1]=a.u[2]=a.u[3]=0; }
        bp += __shfl_xor(bp, 16);                 // qd0+qd1
        if (qd == 0) bias_s[(w*2+im)*16 + l15] = bp;
        fa[im] = a.s;
    }

    f32x4_t acc[2][8];
    #pragma unroll
    for (int im = 0; im < 2; ++im)
        #pragma unroll
        for (int nt = 0; nt < 8; ++nt) acc[im][nt] = (f32x4_t){0.f,0.f,0.f,0.f};
    #pragma unroll
    for (int nt = 0; nt < 8; ++nt) {
        short8_t b = *(const short8_t*)&Wc1b[(nt*16 + l15)*32 + qd*8];
        acc[0][nt] = __builtin_amdgcn_mfma_f32_16x16x32_bf16(fa[0], b, acc[0][nt], 0,0,0);
        acc[1][nt] = __builtin_amdgcn_mfma_f32_16x16x32_bf16(fa[1], b, acc[1][nt], 0,0,0);
    }
    #pragma unroll
    for (int im = 0; im < 2; ++im)
        #pragma unroll
        for (int nt = 0; nt < 8; ++nt) {
            int n = nt*16 + l15;
            float bv = bc1[n];
            #pragma unroll
            for (int r = 0; r < 4; ++r)
                cand_s[((w*2+im)*16 + qd*4 + r)*136 + n] =
                    f2bf(gelu_f(acc[im][nt][r] + bv));
        }
    __syncthreads();   // cand1 (and bias_s) visible before GEMM2 reads

    // ---- GEMM2 ------------------------------------------------------------
    #pragma unroll
    for (int im = 0; im < 2; ++im)
        #pragma unroll
        for (int nt = 0; nt < 8; ++nt) acc[im][nt] = (f32x4_t){0.f,0.f,0.f,0.f};
    #pragma unroll
    for (int kc = 0; kc < 4; ++kc) {
        int k0 = kc*32 + qd*8;
        short8_t a0 = *(const short8_t*)&cand_s[((w*2+0)*16 + l15)*136 + k0];
        short8_t a1 = *(const short8_t*)&cand_s[((w*2+1)*16 + l15)*136 + k0];
        #pragma unroll
        for (int nt = 0; nt < 8; ++nt) {
            short8_t b = *(const short8_t*)&Wc2b[(nt*16 + l15)*128 + k0];
            acc[0][nt] = __builtin_amdgcn_mfma_f32_16x16x32_bf16(a0, b, acc[0][nt], 0,0,0);
            acc[1][nt] = __builtin_amdgcn_mfma_f32_16x16x32_bf16(a1, b, acc[1][nt], 0,0,0);
        }
    }
    __syncthreads();   // all cand1 reads complete before rewrite
    #pragma unroll
    for (int im = 0; im < 2; ++im)
        #pragma unroll
        for (int nt = 0; nt < 8; ++nt) {
            int n = nt*16 + l15;
            float bv = bc2[n];
            #pragma unroll
            for (int r = 0; r < 4; ++r)
                cand_s[((w*2+im)*16 + qd*4 + r)*136 + n] =
                    f2bf(gelu_f(acc[im][nt][r] + bv));
        }
    __syncthreads();   // cand2 visible before GEMM3 reads

    // ---- GEMM3: [cand2 | q*cand2] @ Wfu^T (K=256 folded) ------------------
    #pragma unroll
    for (int im = 0; im < 2; ++im)
        #pragma unroll
        for (int nt = 0; nt < 8; ++nt) acc[im][nt] = (f32x4_t){0.f,0.f,0.f,0.f};
    const float* qrow = Qb + (long)node*HD;
    #pragma unroll
    for (int kc = 0; kc < 4; ++kc) {
        int k0 = kc*32 + qd*8;
        short8_t a0 = *(const short8_t*)&cand_s[((w*2+0)*16 + l15)*136 + k0];
        short8_t a1 = *(const short8_t*)&cand_s[((w*2+1)*16 + l15)*136 + k0];
        #pragma unroll
        for (int nt = 0; nt < 8; ++nt) {
            short8_t b = *(const short8_t*)&Wfu[(nt*16 + l15)*256 + k0];
            acc[0][nt] = __builtin_amdgcn_mfma_f32_16x16x32_bf16(a0, b, acc[0][nt], 0,0,0);
            acc[1][nt] = __builtin_amdgcn_mfma_f32_16x16x32_bf16(a1, b, acc[1][nt], 0,0,0);
        }
        float4 qa = *(const float4*)&qrow[k0];
        float4 qb = *(const float4*)&qrow[k0+4];
        short8_t aq0 = mulq2(a0, qa, qb);
        short8_t aq1 = mulq2(a1, qa, qb);
        #pragma unroll
        for (int nt = 0; nt < 8; ++nt) {
            short8_t b = *(const short8_t*)&Wfu[(nt*16 + l15)*256 + 128 + k0];
            acc[0][nt] = __builtin_amdgcn_mfma_f32_16x16x32_bf16(aq0, b, acc[0][nt], 0,0,0);
            acc[1][nt] = __builtin_amdgcn_mfma_f32_16x16x32_bf16(aq1, b, acc[1][nt], 0,0,0);
        }
    }

    // ---- epilogue ---------------------------------------------------------
    float bs1v[8], ws2v[8];
    #pragma unroll
    for (int nt = 0; nt < 8; ++nt) {
        int n = nt*16 + l15;
        bs1v[nt] = bs1[n];
        ws2v[nt] = Ws2[n];
    }
    float b2v = bs2[0];
    #pragma unroll
    for (int im = 0; im < 2; ++im)
        #pragma unroll
        for (int r = 0; r < 4; ++r) {
            float p = 0.f;
            #pragma unroll
            for (int nt = 0; nt < 8; ++nt)
                p += gelu_f(acc[im][nt][r] + bs1v[nt]) * ws2v[nt];
            p += __shfl_xor(p,1); p += __shfl_xor(p,2);
            p += __shfl_xor(p,4); p += __shfl_xor(p,8);
            if (l15 == 0) {
                int lrow = (w*2+im)*16 + qd*4 + r;
                long row = r0 + lrow;
                float lg = p + b2v + bias_s[lrow];
                float m = am[row];
                if ((lrow & 63) == 0 && noval) m = 1.0f;
                out[row] = (m > 0.f) ? lg : NEGV;
            }
        }
}

// ---------------------------------------------------------------------------
extern "C" void kernel_launch(void* const* d_in, const int* in_sizes, int n_in,
                              void* d_out, int out_size, void* d_ws, size_t ws_size,
                              hipStream_t stream)
{
    const float* X   = (const float*)d_in[0];
    const float* CF  = (const float*)d_in[1];
    const int*   ADJ = (const int*)d_in[2];
    const float* AM  = (const float*)d_in[3];
    const float* W1  = (const float*)d_in[4];
    const float* A1S = (const float*)d_in[5];
    const float* A1D = (const float*)d_in[6];
    const float* W2  = (const float*)d_in[7];
    const float* A2S = (const float*)d_in[8];
    const float* A2D = (const float*)d_in[9];
    const float* LNW = (const float*)d_in[10];
    const float* LNB = (const float*)d_in[11];
    const float* WC1 = (const float*)d_in[12];
    const float* BC1 = (const float*)d_in[13];
    const float* WC2 = (const float*)d_in[14];
    const float* BC2 = (const float*)d_in[15];
    const float* WQ  = (const float*)d_in[16];
    const float* BQ  = (const float*)d_in[17];
    const float* WS1 = (const float*)d_in[18];
    const float* BS1 = (const float*)d_in[19];
    const float* WS2 = (const float*)d_in[20];
    const float* BS2 = (const float*)d_in[21];
    float* OUT = (float*)d_out;

    float* ws = (float*)d_ws;
    float*    G1   = ws;                               // 524288
    float*    Qb   = ws + 524288;                      // 524288
    float*    sdv  = ws + 1048576;                     // 8192 (s,d)
    float*    denp = ws + 1056768;                     // 32768
    short*    Htb  = (short*)(ws + 1089536);           // 524288 shorts
    unsigned* adjb = (unsigned*)(ws + 1351680);        // 524288 words
    short*    Wc1b = (short*)(ws + 1875968);           // 4096 shorts
    short*    Wc2b = (short*)(ws + 1878016);           // 16384 shorts
    short*    Wfu  = (short*)(ws + 1886208);           // 32768 shorts
    float*    nump = ws + 1902592;                     // 4194304

    // prep: adjacency pack + candidate weight conversions
    prep_k<<<2056, 256, 0, stream>>>(ADJ, WC1, WC2, WS1, adjb, Wc1b, Wc2b, Wfu);

    // GAT layer 1
    gatin_k3<64, 0, 0><<<256, 256, 0, stream>>>(
        X, W1, nullptr, nullptr, nullptr, nullptr, nullptr,
        A1S, A1D, sdv, Htb, nullptr, nullptr);
    agg_k4<<<dim3(128, NSEG), 256, 0, stream>>>(adjb, sdv, Htb, nump, denp);

    // GAT layer 2 (reduce folded in)
    gatin_k3<128, 1, 0><<<256, 256, 0, stream>>>(
        nullptr, W2, nump, denp, G1, nullptr, nullptr,
        A2S, A2D, sdv, Htb, nullptr, nullptr);
    agg_k4<<<dim3(128, NSEG), 256, 0, stream>>>(adjb, sdv, Htb, nump, denp);

    // residual + LayerNorm + query projection (all folded)
    gatin_k3<128, 2, 1><<<256, 256, 0, stream>>>(
        nullptr, WQ, nump, denp, G1, LNW, LNB,
        nullptr, nullptr, nullptr, nullptr, BQ, Qb);

    // fused candidate head
    cand_k4<<<2048, 256, 0, stream>>>(CF, AM, Qb, Wc1b, Wc2b, Wfu,
                                      BC1, BC2, BS1, WS2, BS2, OUT);
}